// Round 7
// baseline (392.469 us; speedup 1.0000x reference)
//
#include <hip/hip_runtime.h>
#include <hip/hip_bf16.h>

// Problem constants
#define H_   32
#define KV_  8
#define D_   128
#define S_   2048
#define HID_ 4096

typedef __attribute__((ext_vector_type(8))) short short8;
typedef short8 short8a __attribute__((may_alias));
typedef __attribute__((ext_vector_type(4))) float f32x4;
typedef unsigned short u16;
typedef unsigned int u32;

__device__ __forceinline__ u16 f2bf(float f) {
  union { float f; unsigned u; } a; a.f = f;
  unsigned r = a.u + 0x7fffu + ((a.u >> 16) & 1u);   // RNE
  return (u16)(r >> 16);
}
__device__ __forceinline__ float bf2f(u16 h) {
  union { unsigned u; float f; } a; a.u = ((unsigned)h) << 16;
  return a.f;
}

#define GLOAD16(g, l) __builtin_amdgcn_global_load_lds( \
    (const __attribute__((address_space(1))) void*)(g), \
    (__attribute__((address_space(3))) void*)(l), 16, 0, 0)

// ---------------- fused fp32 -> bf16 cast of all 4 weights ----------------
__global__ void cast4_kernel(const float* __restrict__ s0, const float* __restrict__ s1,
                             const float* __restrict__ s2, const float* __restrict__ s3,
                             u16* __restrict__ d0, u16* __restrict__ d1,
                             u16* __restrict__ d2, u16* __restrict__ d3,
                             int n0, int n1, int n2, int n3) {
  int total = n0 + n1 + n2 + n3;
  for (int i = blockIdx.x * blockDim.x + threadIdx.x; i < total; i += gridDim.x * blockDim.x) {
    const float* s; u16* d; int k = i;
    if (k < n0) { s = s0; d = d0; }
    else if ((k -= n0) < n1) { s = s1; d = d1; }
    else if ((k -= n1) < n2) { s = s2; d = d2; }
    else { k -= n2; s = s3; d = d3; }
    float4 v = ((const float4*)s)[k];
    ushort4 o;
    o.x = f2bf(v.x); o.y = f2bf(v.y); o.z = f2bf(v.z); o.w = f2bf(v.w);
    ((ushort4*)d)[k] = o;
  }
}

// ---------------- X (HID,S) fp32 -> X^T (S,HID) bf16 ----------------
__global__ __launch_bounds__(256) void transpose_cast_kernel(const float* __restrict__ in,
                                                             u16* __restrict__ out) {
  __shared__ float t[32][33];
  int tx = threadIdx.x & 31, ty = threadIdx.x >> 5;  // 32x8
  int s0 = blockIdx.x * 32, c0 = blockIdx.y * 32;
  #pragma unroll
  for (int i = 0; i < 4; i++)
    t[ty + i * 8][tx] = in[(size_t)(c0 + ty + i * 8) * S_ + s0 + tx];
  __syncthreads();
  #pragma unroll
  for (int i = 0; i < 4; i++)
    out[(size_t)(s0 + ty + i * 8) * HID_ + c0 + tx] = f2bf(t[tx][ty + i * 8]);
}

// ---------------- y += p (split-K reduce) ----------------
__global__ void reduce_add_kernel(float* __restrict__ y, const float* __restrict__ p, int n4) {
  int i = blockIdx.x * blockDim.x + threadIdx.x;
  int st = gridDim.x * blockDim.x;
  for (; i < n4; i += st) {
    float4 a = ((const float4*)y)[i];
    float4 b = ((const float4*)p)[i];
    a.x += b.x; a.y += b.y; a.z += b.z; a.w += b.w;
    ((float4*)y)[i] = a;
  }
}

// ---------------- BM x 256 bf16 GEMM ----------------
// C = A(MxK) * Bt(NxK)^T. 8 waves (2M x 4N), BK=64, 2-parity LDS, XOR-swizzled,
// one vmcnt(4)/K-tile at ph4, setprio MFMA, bijective XCD swizzle, optional split-K (z).
// PF=true: one-phase-ahead fragment prefetch (4 banks afA/afB/bfA/bfB).
__device__ __forceinline__ short8 ldsfrag(const u16* base, int row, int ks, int kg) {
  int cb = (ks * 64 + kg * 16) ^ ((row & 7) << 4);
  return *(const short8a*)((const char*)base + row * 128 + cb);
}

template<int BM, bool PF>
__global__ __launch_bounds__(512, 2) void gemm_t(const u16* __restrict__ A, const u16* __restrict__ Bt,
    const float* __restrict__ bq, const float* __restrict__ bk, const float* __restrict__ bv,
    u16* __restrict__ Cb, float* __restrict__ Cf0, float* __restrict__ Cf1,
    int N, int K, int kPerSplit) {
  constexpr int CA = BM / 64;        // A chunks/K-tile (1 gload/thread each)
  constexpr int CA1 = (CA + 1) / 2;
  constexpr int MI = BM / 64;        // 16-row frags per quadrant
  __shared__ alignas(16) u16 Asl[2][BM * 64];
  __shared__ alignas(16) u16 Bsl[2][256 * 64];
  int tid = threadIdx.x, wid = tid >> 6, lane = tid & 63;
  int lr = lane & 15, kg = lane >> 4;
  // bijective XCD swizzle (per z-slice)
  int gx = gridDim.x, nwg = gx * gridDim.y;
  int lid = blockIdx.y * gx + blockIdx.x;
  int q = nwg >> 3, r = nwg & 7;
  int xcd = lid & 7, idx = lid >> 3;
  int swz = (xcd < r ? xcd * (q + 1) : r * (q + 1) + (xcd - r) * q) + idx;
  int m0 = (swz / gx) * BM, n0 = (swz % gx) * 256;
  int k0 = blockIdx.z * kPerSplit;
  int NT = kPerSplit >> 6;
  float* Cf = blockIdx.z ? Cf1 : Cf0;
  const u16* Ap = A + (size_t)m0 * K + k0;
  const u16* Bp = Bt + (size_t)n0 * K + k0;
  int wm = wid >> 2, wn = wid & 3;
  f32x4 acc[2][2][MI][2] = {};

  auto STAGEC = [&](const u16* gp, int tile, int chunk, u16* base) {
    int p = tid * 16;
    int row = (chunk << 6) + (p >> 7);
    int gcb = (p & 127) ^ ((row & 7) << 4);
    const char* src = (const char*)gp + ((size_t)row * K + (tile << 6)) * 2 + gcb;
    char* dst = (char*)base + (chunk << 13) + (wid << 10);
    GLOAD16(src, dst);
  };
  auto LDA = [&](short8 (&af)[MI][2], const u16* base, int qm) {
    #pragma unroll
    for (int mi = 0; mi < MI; mi++)
      #pragma unroll
      for (int ks = 0; ks < 2; ks++)
        af[mi][ks] = ldsfrag(base, wm * (BM / 2) + qm * (BM / 4) + mi * 16 + lr, ks, kg);
  };
  auto LDB = [&](short8 (&bf)[2][2], const u16* base, int qn) {
    #pragma unroll
    for (int ni = 0; ni < 2; ni++)
      #pragma unroll
      for (int ks = 0; ks < 2; ks++)
        bf[ni][ks] = ldsfrag(base, wn * 64 + qn * 32 + ni * 16 + lr, ks, kg);
  };
  auto MM = [&](f32x4 (&a)[MI][2], short8 (&af)[MI][2], short8 (&bf)[2][2]) {
    __builtin_amdgcn_s_setprio(1);
    #pragma unroll
    for (int ks = 0; ks < 2; ks++)
      #pragma unroll
      for (int mi = 0; mi < MI; mi++)
        #pragma unroll
        for (int ni = 0; ni < 2; ni++)
          a[mi][ni] = __builtin_amdgcn_mfma_f32_16x16x32_bf16(af[mi][ks], bf[ni][ks], a[mi][ni], 0, 0, 0);
    __builtin_amdgcn_s_setprio(0);
  };
  #define BAR() __builtin_amdgcn_s_barrier()
  #define SB()  __builtin_amdgcn_sched_barrier(0)
  #define VMCNT(n) asm volatile("s_waitcnt vmcnt(" #n ")" ::: "memory")

  // prologue: A0 (CA), B0 (4), B1 (4); drain A0+B0, keep B1 in flight
  #pragma unroll
  for (int c = 0; c < CA; c++) STAGEC(Ap, 0, c, &Asl[0][0]);
  #pragma unroll
  for (int c = 0; c < 4; c++) STAGEC(Bp, 0, c, &Bsl[0][0]);
  #pragma unroll
  for (int c = 0; c < 4; c++) STAGEC(Bp, 1, c, &Bsl[1][0]);
  VMCNT(4);
  BAR();

  if constexpr (PF) {
    // ---- prefetch schedule: reads one phase ahead of use ----
    short8 afA[MI][2], afB[MI][2], bfA[2][2], bfB[2][2];
    SB();
    LDA(afA, &Asl[0][0], 0); LDB(bfA, &Bsl[0][0], 0);   // T0 ph1 frags
    for (int T = 0; T < NT; T++) {
      int par = T & 1;
      u16* aC = &Asl[par][0];     u16* bC = &Bsl[par][0];
      u16* aN = &Asl[par ^ 1][0]; u16* bN = &Bsl[par ^ 1][0];
      int tA = T + 1 < NT ? T + 1 : NT - 1;   // tail clamps: benign rewrites
      int tB = T + 2 < NT ? T + 2 : NT - 1;
      // ph1: MM(0,0)[afA,bfA] || read bfB(T), afB(T); stage A(T+1) first chunks
      #pragma unroll
      for (int c = 0; c < CA1; c++) STAGEC(Ap, tA, c, aN);
      SB(); BAR(); SB();
      LDB(bfB, bC, 1); LDA(afB, aC, 1);
      MM(acc[0][0], afA, bfA);
      BAR();
      // ph2: MM(0,1)[afA,bfB]; stage rest of A(T+1)
      #pragma unroll
      for (int c = CA1; c < CA; c++) STAGEC(Ap, tA, c, aN);
      SB(); BAR();
      MM(acc[0][1], afA, bfB);
      BAR();
      // ph3: MM(1,0)[afB,bfA]; stage B(T+2) chunks 0,1 (B(T) regs already consumed)
      STAGEC(Bp, tB, 0, bC); STAGEC(Bp, tB, 1, bC);
      SB(); BAR();
      MM(acc[1][0], afB, bfA);
      BAR();
      // ph4: MM(1,1)[afB,bfB] || prefetch afA,bfA of T+1; stage B(T+2) 2,3; vmcnt -> T+1 landed
      STAGEC(Bp, tB, 2, bC); STAGEC(Bp, tB, 3, bC);
      VMCNT(4);
      SB(); BAR(); SB();
      LDA(afA, aN, 0); LDB(bfA, bN, 0);
      MM(acc[1][1], afB, bfB);
      BAR();
    }
  } else {
    // ---- round-5 proven schedule (in-phase reads before barrier) ----
    short8 af[MI][2], bfA[2][2], bfB[2][2];
    for (int T = 0; T < NT; T++) {
      int par = T & 1;
      u16* aC = &Asl[par][0];
      u16* bC = &Bsl[par][0];
      u16* aN = &Asl[par ^ 1][0];
      int tA = T + 1 < NT ? T + 1 : NT - 1;
      int tB = T + 2 < NT ? T + 2 : NT - 1;
      LDA(af, aC, 0); LDB(bfA, bC, 0);
      #pragma unroll
      for (int c = 0; c < CA1; c++) STAGEC(Ap, tA, c, aN);
      SB(); BAR();
      MM(acc[0][0], af, bfA);
      BAR();
      LDB(bfB, bC, 1);
      #pragma unroll
      for (int c = CA1; c < CA; c++) STAGEC(Ap, tA, c, aN);
      SB(); BAR();
      MM(acc[0][1], af, bfB);
      BAR();
      LDA(af, aC, 1);
      STAGEC(Bp, tB, 0, bC); STAGEC(Bp, tB, 1, bC);
      SB(); BAR();
      MM(acc[1][0], af, bfA);
      BAR();
      STAGEC(Bp, tB, 2, bC); STAGEC(Bp, tB, 3, bC);
      VMCNT(4);
      SB(); BAR();
      MM(acc[1][1], af, bfB);
      BAR();
    }
  }
  #undef BAR
  #undef SB
  #undef VMCNT

  // epilogue
  #pragma unroll
  for (int qm = 0; qm < 2; qm++)
    #pragma unroll
    for (int qn = 0; qn < 2; qn++)
      #pragma unroll
      for (int mi = 0; mi < MI; mi++)
        #pragma unroll
        for (int ni = 0; ni < 2; ni++) {
          int col = n0 + wn * 64 + qn * 32 + ni * 16 + lr;
          int rbase = m0 + wm * (BM / 2) + qm * (BM / 4) + mi * 16 + kg * 4;
          #pragma unroll
          for (int rr = 0; rr < 4; rr++) {
            int row = rbase + rr;
            float v = acc[qm][qn][mi][ni][rr];
            if (bq) v += row < 4096 ? bq[row] : (row < 5120 ? bk[row - 4096] : bv[row - 5120]);
            if (Cf) Cf[(size_t)row * N + col] = v;
            else    Cb[(size_t)row * N + col] = f2bf(v);
          }
        }
}

// ---------------- RoPE + transpose: in (nH*D, S) bf16 -> out (nH, S, D) bf16 ----------------
__global__ __launch_bounds__(256) void rope_transpose_kernel(const u16* __restrict__ in,
                                                             u16* __restrict__ out,
                                                             const float* __restrict__ cp,
                                                             const float* __restrict__ sp,
                                                             float oscale) {
  __shared__ u16 t[128][33];
  int h = blockIdx.x;
  int s0 = blockIdx.y * 32;
  int tid = threadIdx.x;
  #pragma unroll
  for (int i = 0; i < 16; i++) {
    int idx = tid + i * 256;
    int row = idx >> 5, sc = idx & 31;
    t[row][sc] = in[(size_t)(h * 128 + row) * S_ + s0 + sc];
  }
  __syncthreads();
  int d = tid & 127, sh = tid >> 7;
  int dl = d & 63;
  bool hi = d >= 64;
  #pragma unroll
  for (int j = 0; j < 16; j++) {
    int sl = sh * 16 + j;
    int s = s0 + sl;
    float x = bf2f(t[d][sl]);
    float p = bf2f(t[d ^ 64][sl]);
    float c  = cp[(size_t)s * D_ + dl];
    float sn = sp[(size_t)s * D_ + dl];
    float o = hi ? fmaf(p, sn, x * c) : fmaf(-p, sn, x * c);
    out[((size_t)h * S_ + s) * D_ + d] = f2bf(o * oscale);
  }
}

// ---------------- flash attention v2 (causal GQA, swapped-QK, staged KV) ----------------
__global__ __launch_bounds__(256) void attn_v2(const u16* __restrict__ Q, const u16* __restrict__ K,
                                               const u16* __restrict__ V, u16* __restrict__ Ot) {
  __shared__ alignas(16) u16 Ks[2][64 * 128];
  __shared__ alignas(16) u16 Vs[2][128 * 64];
  __shared__ alignas(16) u16 Pl[4][2][16 * 64];
  int h = blockIdx.x;
  int qtile = (int)(gridDim.y - 1) - (int)blockIdx.y;   // heavy first
  int kv = h >> 2;
  int tid = threadIdx.x, wid = tid >> 6, lane = tid & 63;
  int lr = lane & 15, kg = lane >> 4;
  int q0w = qtile * 128 + wid * 32;
  const u16* Qb = Q + ((size_t)h * S_ + q0w) * D_;
  const u16* Kb = K + (size_t)kv * S_ * D_;
  const u16* Vb = V + (size_t)kv * D_ * S_;
  int sw = (lr & 7) << 3;

  short8 qf[2][4];
  #pragma unroll
  for (int m = 0; m < 2; m++)
    #pragma unroll
    for (int kk = 0; kk < 4; kk++)
      qf[m][kk] = *(const short8a*)(Qb + (size_t)(m * 16 + lr) * D_ + kk * 32 + kg * 8);

  f32x4 acc[2][8] = {};
  float mreg[2] = {-1e30f, -1e30f};
  float lsum[2] = {0.f, 0.f};

  int krow[4], kcb[4], vrow[4], vcb[4];
  #pragma unroll
  for (int j = 0; j < 4; j++) {
    int c = wid * 4 + j;
    int o = c * 1024 + lane * 16;
    krow[j] = o >> 8;
    kcb[j] = (o & 255) ^ ((krow[j] & 7) << 4);
    vrow[j] = o >> 7;
    vcb[j] = (o & 127) ^ ((vrow[j] & 7) << 4);
  }

  int nlt = 2 * qtile + 2;
  #pragma unroll
  for (int j = 0; j < 4; j++) {
    int c = wid * 4 + j;
    GLOAD16((const char*)Kb + ((size_t)krow[j] * D_) * 2 + kcb[j], (char*)Ks[0] + c * 1024);
    GLOAD16((const char*)Vb + ((size_t)vrow[j] * S_) * 2 + vcb[j], (char*)Vs[0] + c * 1024);
  }
  int cur = 0;
  for (int t = 0; t < nlt; t++) {
    __syncthreads();
    if (t + 1 < nlt) {
      int l1 = (t + 1) * 64;
      #pragma unroll
      for (int j = 0; j < 4; j++) {
        int c = wid * 4 + j;
        GLOAD16((const char*)Kb + ((size_t)(l1 + krow[j]) * D_) * 2 + kcb[j],
                (char*)Ks[cur ^ 1] + c * 1024);
        GLOAD16((const char*)Vb + ((size_t)vrow[j] * S_ + l1) * 2 + vcb[j],
                (char*)Vs[cur ^ 1] + c * 1024);
      }
    }
    int l0 = t * 64;
    bool act0 = l0 <= q0w + 15;
    bool act1 = l0 <= q0w + 31;
    if (act1) {
      const u16* Kc = Ks[cur];
      const u16* Vc = Vs[cur];
      f32x4 st[2][4] = {};
      #pragma unroll
      for (int ls = 0; ls < 4; ls++) {
        short8 kf[4];
        #pragma unroll
        for (int kk = 0; kk < 4; kk++)
          kf[kk] = *(const short8a*)&Kc[(ls * 16 + lr) * 128 + ((kk * 32 + kg * 8) ^ sw)];
        #pragma unroll
        for (int kk = 0; kk < 4; kk++) {
          st[0][ls] = __builtin_amdgcn_mfma_f32_16x16x32_bf16(kf[kk], qf[0][kk], st[0][ls], 0, 0, 0);
          st[1][ls] = __builtin_amdgcn_mfma_f32_16x16x32_bf16(kf[kk], qf[1][kk], st[1][ls], 0, 0, 0);
        }
      }
      #pragma unroll
      for (int m = 0; m < 2; m++) {
        bool act = m ? act1 : act0;
        if (!act) continue;
        int qrow = q0w + m * 16 + lr;
        if (l0 + 63 > q0w + m * 16) {
          #pragma unroll
          for (int ls = 0; ls < 4; ls++)
            #pragma unroll
            for (int rr = 0; rr < 4; rr++) {
              int l = l0 + ls * 16 + kg * 4 + rr;
              st[m][ls][rr] = (l <= qrow) ? st[m][ls][rr] : -1e30f;
            }
        }
        float rmax;
        {
          float a0 = fmaxf(fmaxf(st[m][0][0], st[m][0][1]), fmaxf(st[m][0][2], st[m][0][3]));
          float a1 = fmaxf(fmaxf(st[m][1][0], st[m][1][1]), fmaxf(st[m][1][2], st[m][1][3]));
          float a2 = fmaxf(fmaxf(st[m][2][0], st[m][2][1]), fmaxf(st[m][2][2], st[m][2][3]));
          float a3 = fmaxf(fmaxf(st[m][3][0], st[m][3][1]), fmaxf(st[m][3][2], st[m][3][3]));
          rmax = fmaxf(fmaxf(a0, a1), fmaxf(a2, a3));
        }
        rmax = fmaxf(rmax, __shfl_xor(rmax, 16, 64));
        rmax = fmaxf(rmax, __shfl_xor(rmax, 32, 64));
        if (__any(rmax > mreg[m] + 8.0f)) {
          float nm = fmaxf(mreg[m], rmax);
          float f = __builtin_amdgcn_exp2f(mreg[m] - nm);
          mreg[m] = nm;
          lsum[m] *= f;
          float fr0 = __shfl(f, kg * 4 + 0, 64);
          float fr1 = __shfl(f, kg * 4 + 1, 64);
          float fr2 = __shfl(f, kg * 4 + 2, 64);
          float fr3 = __shfl(f, kg * 4 + 3, 64);
          #pragma unroll
          for (int dc = 0; dc < 8; dc++) {
            acc[m][dc][0] *= fr0; acc[m][dc][1] *= fr1;
            acc[m][dc][2] *= fr2; acc[m][dc][3] *= fr3;
          }
        }
        float e[4][4];
        #pragma unroll
        for (int ls = 0; ls < 4; ls++)
          #pragma unroll
          for (int rr = 0; rr < 4; rr++)
            e[ls][rr] = __builtin_amdgcn_exp2f(st[m][ls][rr] - mreg[m]);
        float rs = 0.f;
        #pragma unroll
        for (int ls = 0; ls < 4; ls++)
          rs += (e[ls][0] + e[ls][1]) + (e[ls][2] + e[ls][3]);
        rs += __shfl_xor(rs, 16, 64);
        rs += __shfl_xor(rs, 32, 64);
        lsum[m] += rs;
        u16* Pw = &Pl[wid][m][0];
        #pragma unroll
        for (int ls = 0; ls < 4; ls++) {
          __hip_bfloat162 p01 = __float22bfloat162_rn(float2{e[ls][0], e[ls][1]});
          __hip_bfloat162 p23 = __float22bfloat162_rn(float2{e[ls][2], e[ls][3]});
          uint2 pk;
          pk.x = *(u32*)&p01;
          pk.y = *(u32*)&p23;
          *(uint2*)&Pw[lr * 64 + ((ls * 16 + kg * 4) ^ sw)] = pk;
        }
      }
      #pragma unroll
      for (int kk = 0; kk < 2; kk++) {
        short8 pf0 = {}, pf1;
        if (act0) pf0 = *(const short8a*)&Pl[wid][0][lr * 64 + ((kk * 32 + kg * 8) ^ sw)];
        pf1 = *(const short8a*)&Pl[wid][1][lr * 64 + ((kk * 32 + kg * 8) ^ sw)];
        #pragma unroll
        for (int dc = 0; dc < 8; dc++) {
          short8 vf = *(const short8a*)&Vc[(dc * 16 + lr) * 64 + ((kk * 32 + kg * 8) ^ sw)];
          if (act0) acc[0][dc] = __builtin_amdgcn_mfma_f32_16x16x32_bf16(pf0, vf, acc[0][dc], 0, 0, 0);
          acc[1][dc] = __builtin_amdgcn_mfma_f32_16x16x32_bf16(pf1, vf, acc[1][dc], 0, 0, 0);
        }
      }
    }
    cur ^= 1;
  }
  #pragma unroll
  for (int m = 0; m < 2; m++) {
    float inv0 = 1.0f / __shfl(lsum[m], kg * 4 + 0, 64);
    float inv1 = 1.0f / __shfl(lsum[m], kg * 4 + 1, 64);
    float inv2 = 1.0f / __shfl(lsum[m], kg * 4 + 2, 64);
    float inv3 = 1.0f / __shfl(lsum[m], kg * 4 + 3, 64);
    #pragma unroll
    for (int dc = 0; dc < 8; dc++) {
      int col = h * D_ + dc * 16 + lr;
      int qg = q0w + m * 16 + kg * 4;
      Ot[(size_t)(qg + 0) * HID_ + col] = f2bf(acc[m][dc][0] * inv0);
      Ot[(size_t)(qg + 1) * HID_ + col] = f2bf(acc[m][dc][1] * inv1);
      Ot[(size_t)(qg + 2) * HID_ + col] = f2bf(acc[m][dc][2] * inv2);
      Ot[(size_t)(qg + 3) * HID_ + col] = f2bf(acc[m][dc][3] * inv3);
    }
  }
}

// ---------------- workspace layout (bytes) ----------------
static constexpr size_t OFF_WQKV = 0;           // 50331648 (6144x4096 bf16); reused post-QKV-gemm
static constexpr size_t OFF_WO   = 50331648;    // 33554432 (4096x4096 bf16)
static constexpr size_t OFF_XT   = 83886080;    // 16777216; at WO-time reused (with QKVC) as P1 (33.5MB)
static constexpr size_t OFF_QKVC = 100663296;   // 25165824 -> total 125829120

// log2(e)/sqrt(128): folds softmax scale + base-2 exp into Q
#define QSCALE 0.1275176329533421f

extern "C" void kernel_launch(void* const* d_in, const int* in_sizes, int n_in,
                              void* d_out, int out_size, void* d_ws, size_t ws_size,
                              hipStream_t stream) {
  const float* x    = (const float*)d_in[0];
  const float* wq   = (const float*)d_in[1];
  const float* bq   = (const float*)d_in[2];
  const float* wk   = (const float*)d_in[3];
  const float* bk   = (const float*)d_in[4];
  const float* wv   = (const float*)d_in[5];
  const float* bv   = (const float*)d_in[6];
  const float* wo   = (const float*)d_in[7];
  const float* cosP = (const float*)d_in[8];
  const float* sinP = (const float*)d_in[9];
  char* ws = (char*)d_ws;
  u16* WQKV = (u16*)(ws + OFF_WQKV);
  u16* WO   = (u16*)(ws + OFF_WO);
  u16* XT   = (u16*)(ws + OFF_XT);
  u16* QKVC = (u16*)(ws + OFF_QKVC);
  u16* QT   = QKVC;
  u16* KT   = QKVC + (size_t)4096 * S_;
  u16* VB   = QKVC + (size_t)5120 * S_;
  u16* QATT = (u16*)(ws + 0);
  u16* KATT = (u16*)(ws + 16777216);
  u16* OT   = (u16*)(ws + 20971520);
  float* P1 = (float*)(ws + OFF_XT);   // XT+QKVC regions dead at WO time (33.5MB)
  float* y = (float*)d_out;

  // 1) fused weight casts
  cast4_kernel<<<2048, 256, 0, stream>>>(
      wq, wk, wv, wo,
      WQKV, WQKV + (size_t)4096 * HID_, WQKV + (size_t)5120 * HID_, WO,
      (HID_ * HID_) / 4, (KV_ * D_ * HID_) / 4, (KV_ * D_ * HID_) / 4, (HID_ * HID_) / 4);
  // 2) X^T
  transpose_cast_kernel<<<dim3(S_ / 32, HID_ / 32), 256, 0, stream>>>(x, XT);
  // 3) fused QKV projection (M=6144), BM=192, prefetch schedule, 256 blocks
  gemm_t<192, true><<<dim3(S_ / 256, 6144 / 192, 1), 512, 0, stream>>>(
      WQKV, XT, bq, bk, bv, QKVC, nullptr, nullptr, S_, HID_, HID_);
  // 4) RoPE + transpose
  rope_transpose_kernel<<<dim3(H_, S_ / 32), 256, 0, stream>>>(QT, QATT, cosP, sinP, QSCALE);
  rope_transpose_kernel<<<dim3(KV_, S_ / 32), 256, 0, stream>>>(KT, KATT, cosP, sinP, 1.0f);
  // 5) causal GQA flash attention -> O^T (S, H*D)
  attn_v2<<<dim3(H_, S_ / 128), 256, 0, stream>>>(QATT, KATT, VB, OT);
  // 6) output projection, BM=256 split-K=2 -> 16x8x2 = 256 blocks; split0 -> y, split1 -> P1
  gemm_t<256, false><<<dim3(S_ / 256, HID_ / 256, 2), 512, 0, stream>>>(
      WO, OT, nullptr, nullptr, nullptr, nullptr, y, P1, S_, HID_, HID_ / 2);
  // 7) y += P1
  reduce_add_kernel<<<2048, 256, 0, stream>>>(y, P1, (HID_ * S_) / 4);
}

// Round 8
// 367.030 us; speedup vs baseline: 1.0693x; 1.0693x over previous
//
#include <hip/hip_runtime.h>
#include <hip/hip_bf16.h>

// Problem constants
#define H_   32
#define KV_  8
#define D_   128
#define S_   2048
#define HID_ 4096

typedef __attribute__((ext_vector_type(8))) short short8;
typedef short8 short8a __attribute__((may_alias));
typedef __attribute__((ext_vector_type(4))) float f32x4;
typedef unsigned short u16;
typedef unsigned int u32;

__device__ __forceinline__ u16 f2bf(float f) {
  union { float f; unsigned u; } a; a.f = f;
  unsigned r = a.u + 0x7fffu + ((a.u >> 16) & 1u);   // RNE
  return (u16)(r >> 16);
}
__device__ __forceinline__ float bf2f(u16 h) {
  union { unsigned u; float f; } a; a.u = ((unsigned)h) << 16;
  return a.f;
}

#define GLOAD16(g, l) __builtin_amdgcn_global_load_lds( \
    (const __attribute__((address_space(1))) void*)(g), \
    (__attribute__((address_space(3))) void*)(l), 16, 0, 0)

// ---------------- fused fp32 -> bf16 cast of all 4 weights ----------------
__global__ void cast4_kernel(const float* __restrict__ s0, const float* __restrict__ s1,
                             const float* __restrict__ s2, const float* __restrict__ s3,
                             u16* __restrict__ d0, u16* __restrict__ d1,
                             u16* __restrict__ d2, u16* __restrict__ d3,
                             int n0, int n1, int n2, int n3) {
  int total = n0 + n1 + n2 + n3;
  for (int i = blockIdx.x * blockDim.x + threadIdx.x; i < total; i += gridDim.x * blockDim.x) {
    const float* s; u16* d; int k = i;
    if (k < n0) { s = s0; d = d0; }
    else if ((k -= n0) < n1) { s = s1; d = d1; }
    else if ((k -= n1) < n2) { s = s2; d = d2; }
    else { k -= n2; s = s3; d = d3; }
    float4 v = ((const float4*)s)[k];
    ushort4 o;
    o.x = f2bf(v.x); o.y = f2bf(v.y); o.z = f2bf(v.z); o.w = f2bf(v.w);
    ((ushort4*)d)[k] = o;
  }
}

// ---------------- X (HID,S) fp32 -> X^T (S,HID) bf16 ----------------
__global__ __launch_bounds__(256) void transpose_cast_kernel(const float* __restrict__ in,
                                                             u16* __restrict__ out) {
  __shared__ float t[32][33];
  int tx = threadIdx.x & 31, ty = threadIdx.x >> 5;  // 32x8
  int s0 = blockIdx.x * 32, c0 = blockIdx.y * 32;
  #pragma unroll
  for (int i = 0; i < 4; i++)
    t[ty + i * 8][tx] = in[(size_t)(c0 + ty + i * 8) * S_ + s0 + tx];
  __syncthreads();
  #pragma unroll
  for (int i = 0; i < 4; i++)
    out[(size_t)(s0 + ty + i * 8) * HID_ + c0 + tx] = f2bf(t[tx][ty + i * 8]);
}

__device__ __forceinline__ short8 ldsfrag(const u16* base, int row, int ks, int kg) {
  int cb = (ks * 64 + kg * 16) ^ ((row & 7) << 4);
  return *(const short8a*)((const char*)base + row * 128 + cb);
}

// ---------------- BM x 256 bf16 GEMM (round-6 proven schedule, 8 waves) ----------------
template<int BM>
__global__ __launch_bounds__(512, 2) void gemm_t(const u16* __restrict__ A, const u16* __restrict__ Bt,
    const float* __restrict__ bq, const float* __restrict__ bk, const float* __restrict__ bv,
    u16* __restrict__ Cb, float* __restrict__ Cf, int N, int K) {
  constexpr int CA = BM / 64;
  constexpr int CA1 = (CA + 1) / 2;
  constexpr int MI = BM / 64;
  __shared__ alignas(16) u16 Asl[2][BM * 64];
  __shared__ alignas(16) u16 Bsl[2][256 * 64];
  int tid = threadIdx.x, wid = tid >> 6, lane = tid & 63;
  int lr = lane & 15, kg = lane >> 4;
  int gx = gridDim.x, nwg = gx * gridDim.y;
  int lid = blockIdx.y * gx + blockIdx.x;
  int q = nwg >> 3, r = nwg & 7;
  int xcd = lid & 7, idx = lid >> 3;
  int swz = (xcd < r ? xcd * (q + 1) : r * (q + 1) + (xcd - r) * q) + idx;
  int m0 = (swz / gx) * BM, n0 = (swz % gx) * 256;
  const u16* Ap = A + (size_t)m0 * K;
  const u16* Bp = Bt + (size_t)n0 * K;
  int wm = wid >> 2, wn = wid & 3;
  f32x4 acc[2][2][MI][2] = {};
  int NT = K >> 6;

  auto STAGEC = [&](const u16* gp, int tile, int chunk, u16* base) {
    int p = tid * 16;
    int row = (chunk << 6) + (p >> 7);
    int gcb = (p & 127) ^ ((row & 7) << 4);
    const char* src = (const char*)gp + ((size_t)row * K + (tile << 6)) * 2 + gcb;
    char* dst = (char*)base + (chunk << 13) + (wid << 10);
    GLOAD16(src, dst);
  };
  auto LDA = [&](short8 (&af)[MI][2], const u16* base, int qm) {
    #pragma unroll
    for (int mi = 0; mi < MI; mi++)
      #pragma unroll
      for (int ks = 0; ks < 2; ks++)
        af[mi][ks] = ldsfrag(base, wm * (BM / 2) + qm * (BM / 4) + mi * 16 + lr, ks, kg);
  };
  auto LDB = [&](short8 (&bf)[2][2], const u16* base, int qn) {
    #pragma unroll
    for (int ni = 0; ni < 2; ni++)
      #pragma unroll
      for (int ks = 0; ks < 2; ks++)
        bf[ni][ks] = ldsfrag(base, wn * 64 + qn * 32 + ni * 16 + lr, ks, kg);
  };
  auto MM = [&](f32x4 (&a)[MI][2], short8 (&af)[MI][2], short8 (&bf)[2][2]) {
    __builtin_amdgcn_s_setprio(1);
    #pragma unroll
    for (int ks = 0; ks < 2; ks++)
      #pragma unroll
      for (int mi = 0; mi < MI; mi++)
        #pragma unroll
        for (int ni = 0; ni < 2; ni++)
          a[mi][ni] = __builtin_amdgcn_mfma_f32_16x16x32_bf16(af[mi][ks], bf[ni][ks], a[mi][ni], 0, 0, 0);
    __builtin_amdgcn_s_setprio(0);
  };
  #define BAR() __builtin_amdgcn_s_barrier()
  #define SB()  __builtin_amdgcn_sched_barrier(0)
  #define VMCNT(n) asm volatile("s_waitcnt vmcnt(" #n ")" ::: "memory")

  #pragma unroll
  for (int c = 0; c < CA; c++) STAGEC(Ap, 0, c, &Asl[0][0]);
  #pragma unroll
  for (int c = 0; c < 4; c++) STAGEC(Bp, 0, c, &Bsl[0][0]);
  #pragma unroll
  for (int c = 0; c < 4; c++) STAGEC(Bp, 1, c, &Bsl[1][0]);
  VMCNT(4);
  BAR();

  short8 af[MI][2], bfA[2][2], bfB[2][2];
  for (int T = 0; T < NT; T++) {
    int par = T & 1;
    u16* aC = &Asl[par][0];
    u16* bC = &Bsl[par][0];
    u16* aN = &Asl[par ^ 1][0];
    int tA = T + 1 < NT ? T + 1 : NT - 1;
    int tB = T + 2 < NT ? T + 2 : NT - 1;
    LDA(af, aC, 0); LDB(bfA, bC, 0);
    #pragma unroll
    for (int c = 0; c < CA1; c++) STAGEC(Ap, tA, c, aN);
    SB(); BAR();
    MM(acc[0][0], af, bfA);
    BAR();
    LDB(bfB, bC, 1);
    #pragma unroll
    for (int c = CA1; c < CA; c++) STAGEC(Ap, tA, c, aN);
    SB(); BAR();
    MM(acc[0][1], af, bfB);
    BAR();
    LDA(af, aC, 1);
    STAGEC(Bp, tB, 0, bC); STAGEC(Bp, tB, 1, bC);
    SB(); BAR();
    MM(acc[1][0], af, bfA);
    BAR();
    STAGEC(Bp, tB, 2, bC); STAGEC(Bp, tB, 3, bC);
    VMCNT(4);
    SB(); BAR();
    MM(acc[1][1], af, bfB);
    BAR();
  }
  #undef BAR
  #undef SB
  #undef VMCNT

  #pragma unroll
  for (int qm = 0; qm < 2; qm++)
    #pragma unroll
    for (int qn = 0; qn < 2; qn++)
      #pragma unroll
      for (int mi = 0; mi < MI; mi++)
        #pragma unroll
        for (int ni = 0; ni < 2; ni++) {
          int col = n0 + wn * 64 + qn * 32 + ni * 16 + lr;
          int rbase = m0 + wm * (BM / 2) + qm * (BM / 4) + mi * 16 + kg * 4;
          #pragma unroll
          for (int rr = 0; rr < 4; rr++) {
            int row = rbase + rr;
            float v = acc[qm][qn][mi][ni][rr];
            if (bq) v += row < 4096 ? bq[row] : (row < 5120 ? bk[row - 4096] : bv[row - 5120]);
            if (Cf) Cf[(size_t)row * N + col] = v;
            else    Cb[(size_t)row * N + col] = f2bf(v);
          }
        }
}

// ---------------- 128x128 bf16 GEMM, 4 waves, 64KB LDS -> 2 blocks/CU ----------------
// Same phase schedule as gemm_t; fp32 output (WO projection). TLP-overlap experiment:
// two independent blocks per CU so one block's MFMA hides the other's barrier drain.
__global__ __launch_bounds__(256, 2) void gemm128(const u16* __restrict__ A, const u16* __restrict__ Bt,
                                                  float* __restrict__ Cf, int N, int K) {
  __shared__ alignas(16) u16 Asl[2][128 * 64];   // 16KB per parity
  __shared__ alignas(16) u16 Bsl[2][128 * 64];
  int tid = threadIdx.x, wid = tid >> 6, lane = tid & 63;
  int lr = lane & 15, kg = lane >> 4;
  int gx = gridDim.x, nwg = gx * gridDim.y;
  int lid = blockIdx.y * gx + blockIdx.x;
  int q = nwg >> 3, r = nwg & 7;
  int xcd = lid & 7, idx = lid >> 3;
  int swz = (xcd < r ? xcd * (q + 1) : r * (q + 1) + (xcd - r) * q) + idx;
  int m0 = (swz / gx) * 128, n0 = (swz % gx) * 128;
  const u16* Ap = A + (size_t)m0 * K;
  const u16* Bp = Bt + (size_t)n0 * K;
  int wr = wid >> 1, wc = wid & 1;   // 2x2 waves, wave tile 64x64
  f32x4 acc[2][2][2][2] = {};        // [qm][qn][mi][ni], quadrant 32x32
  int NT = K >> 6;

  auto STAGEC = [&](const u16* gp, int tile, int chunk, u16* base) {
    int p = (chunk << 12) + tid * 16;        // 4KB chunks (32 rows), 256 threads
    int row = p >> 7;
    int gcb = (p & 127) ^ ((row & 7) << 4);
    const char* src = (const char*)gp + ((size_t)row * K + (tile << 6)) * 2 + gcb;
    char* dst = (char*)base + (chunk << 12) + (wid << 10);
    GLOAD16(src, dst);
  };
  auto LDA = [&](short8 (&af)[2][2], const u16* base, int qm) {
    #pragma unroll
    for (int mi = 0; mi < 2; mi++)
      #pragma unroll
      for (int ks = 0; ks < 2; ks++)
        af[mi][ks] = ldsfrag(base, wr * 64 + qm * 32 + mi * 16 + lr, ks, kg);
  };
  auto LDB = [&](short8 (&bf)[2][2], const u16* base, int qn) {
    #pragma unroll
    for (int ni = 0; ni < 2; ni++)
      #pragma unroll
      for (int ks = 0; ks < 2; ks++)
        bf[ni][ks] = ldsfrag(base, wc * 64 + qn * 32 + ni * 16 + lr, ks, kg);
  };
  auto MM = [&](f32x4 (&a)[2][2], short8 (&af)[2][2], short8 (&bf)[2][2]) {
    __builtin_amdgcn_s_setprio(1);
    #pragma unroll
    for (int ks = 0; ks < 2; ks++)
      #pragma unroll
      for (int mi = 0; mi < 2; mi++)
        #pragma unroll
        for (int ni = 0; ni < 2; ni++)
          a[mi][ni] = __builtin_amdgcn_mfma_f32_16x16x32_bf16(af[mi][ks], bf[ni][ks], a[mi][ni], 0, 0, 0);
    __builtin_amdgcn_s_setprio(0);
  };
  #define BAR() __builtin_amdgcn_s_barrier()
  #define SB()  __builtin_amdgcn_sched_barrier(0)
  #define VMCNT(n) asm volatile("s_waitcnt vmcnt(" #n ")" ::: "memory")

  // prologue: A0(4), B0(4), B1(4); drain to B1-in-flight
  #pragma unroll
  for (int c = 0; c < 4; c++) STAGEC(Ap, 0, c, &Asl[0][0]);
  #pragma unroll
  for (int c = 0; c < 4; c++) STAGEC(Bp, 0, c, &Bsl[0][0]);
  #pragma unroll
  for (int c = 0; c < 4; c++) STAGEC(Bp, 1, c, &Bsl[1][0]);
  VMCNT(4);
  BAR();

  short8 af[2][2], bfA[2][2], bfB[2][2];
  for (int T = 0; T < NT; T++) {
    int par = T & 1;
    u16* aC = &Asl[par][0];
    u16* bC = &Bsl[par][0];
    u16* aN = &Asl[par ^ 1][0];
    int tA = T + 1 < NT ? T + 1 : NT - 1;
    int tB = T + 2 < NT ? T + 2 : NT - 1;
    // ph1
    LDA(af, aC, 0); LDB(bfA, bC, 0);
    STAGEC(Ap, tA, 0, aN); STAGEC(Ap, tA, 1, aN);
    SB(); BAR();
    MM(acc[0][0], af, bfA);
    BAR();
    // ph2
    LDB(bfB, bC, 1);
    STAGEC(Ap, tA, 2, aN); STAGEC(Ap, tA, 3, aN);
    SB(); BAR();
    MM(acc[0][1], af, bfB);
    BAR();
    // ph3
    LDA(af, aC, 1);
    STAGEC(Bp, tB, 0, bC); STAGEC(Bp, tB, 1, bC);
    SB(); BAR();
    MM(acc[1][0], af, bfA);
    BAR();
    // ph4
    STAGEC(Bp, tB, 2, bC); STAGEC(Bp, tB, 3, bC);
    VMCNT(4);
    SB(); BAR();
    MM(acc[1][1], af, bfB);
    BAR();
  }
  #undef BAR
  #undef SB
  #undef VMCNT

  #pragma unroll
  for (int qm = 0; qm < 2; qm++)
    #pragma unroll
    for (int qn = 0; qn < 2; qn++)
      #pragma unroll
      for (int mi = 0; mi < 2; mi++)
        #pragma unroll
        for (int ni = 0; ni < 2; ni++) {
          int col = n0 + wc * 64 + qn * 32 + ni * 16 + lr;
          int rbase = m0 + wr * 64 + qm * 32 + mi * 16 + kg * 4;
          #pragma unroll
          for (int rr = 0; rr < 4; rr++)
            Cf[(size_t)(rbase + rr) * N + col] = acc[qm][qn][mi][ni][rr];
        }
}

// ---------------- RoPE + transpose: in (nH*D, S) bf16 -> out (nH, S, D) bf16 ----------------
__global__ __launch_bounds__(256) void rope_transpose_kernel(const u16* __restrict__ in,
                                                             u16* __restrict__ out,
                                                             const float* __restrict__ cp,
                                                             const float* __restrict__ sp,
                                                             float oscale) {
  __shared__ u16 t[128][33];
  int h = blockIdx.x;
  int s0 = blockIdx.y * 32;
  int tid = threadIdx.x;
  #pragma unroll
  for (int i = 0; i < 16; i++) {
    int idx = tid + i * 256;
    int row = idx >> 5, sc = idx & 31;
    t[row][sc] = in[(size_t)(h * 128 + row) * S_ + s0 + sc];
  }
  __syncthreads();
  int d = tid & 127, sh = tid >> 7;
  int dl = d & 63;
  bool hi = d >= 64;
  #pragma unroll
  for (int j = 0; j < 16; j++) {
    int sl = sh * 16 + j;
    int s = s0 + sl;
    float x = bf2f(t[d][sl]);
    float p = bf2f(t[d ^ 64][sl]);
    float c  = cp[(size_t)s * D_ + dl];
    float sn = sp[(size_t)s * D_ + dl];
    float o = hi ? fmaf(p, sn, x * c) : fmaf(-p, sn, x * c);
    out[((size_t)h * S_ + s) * D_ + d] = f2bf(o * oscale);
  }
}

// ---------------- flash attention v2 (causal GQA, swapped-QK, staged KV) ----------------
__global__ __launch_bounds__(256) void attn_v2(const u16* __restrict__ Q, const u16* __restrict__ K,
                                               const u16* __restrict__ V, u16* __restrict__ Ot) {
  __shared__ alignas(16) u16 Ks[2][64 * 128];
  __shared__ alignas(16) u16 Vs[2][128 * 64];
  __shared__ alignas(16) u16 Pl[4][2][16 * 64];
  int h = blockIdx.x;
  int qtile = (int)(gridDim.y - 1) - (int)blockIdx.y;   // heavy first
  int kv = h >> 2;
  int tid = threadIdx.x, wid = tid >> 6, lane = tid & 63;
  int lr = lane & 15, kg = lane >> 4;
  int q0w = qtile * 128 + wid * 32;
  const u16* Qb = Q + ((size_t)h * S_ + q0w) * D_;
  const u16* Kb = K + (size_t)kv * S_ * D_;
  const u16* Vb = V + (size_t)kv * D_ * S_;
  int sw = (lr & 7) << 3;

  short8 qf[2][4];
  #pragma unroll
  for (int m = 0; m < 2; m++)
    #pragma unroll
    for (int kk = 0; kk < 4; kk++)
      qf[m][kk] = *(const short8a*)(Qb + (size_t)(m * 16 + lr) * D_ + kk * 32 + kg * 8);

  f32x4 acc[2][8] = {};
  float mreg[2] = {-1e30f, -1e30f};
  float lsum[2] = {0.f, 0.f};

  int krow[4], kcb[4], vrow[4], vcb[4];
  #pragma unroll
  for (int j = 0; j < 4; j++) {
    int c = wid * 4 + j;
    int o = c * 1024 + lane * 16;
    krow[j] = o >> 8;
    kcb[j] = (o & 255) ^ ((krow[j] & 7) << 4);
    vrow[j] = o >> 7;
    vcb[j] = (o & 127) ^ ((vrow[j] & 7) << 4);
  }

  int nlt = 2 * qtile + 2;
  #pragma unroll
  for (int j = 0; j < 4; j++) {
    int c = wid * 4 + j;
    GLOAD16((const char*)Kb + ((size_t)krow[j] * D_) * 2 + kcb[j], (char*)Ks[0] + c * 1024);
    GLOAD16((const char*)Vb + ((size_t)vrow[j] * S_) * 2 + vcb[j], (char*)Vs[0] + c * 1024);
  }
  int cur = 0;
  for (int t = 0; t < nlt; t++) {
    __syncthreads();
    if (t + 1 < nlt) {
      int l1 = (t + 1) * 64;
      #pragma unroll
      for (int j = 0; j < 4; j++) {
        int c = wid * 4 + j;
        GLOAD16((const char*)Kb + ((size_t)(l1 + krow[j]) * D_) * 2 + kcb[j],
                (char*)Ks[cur ^ 1] + c * 1024);
        GLOAD16((const char*)Vb + ((size_t)vrow[j] * S_ + l1) * 2 + vcb[j],
                (char*)Vs[cur ^ 1] + c * 1024);
      }
    }
    int l0 = t * 64;
    bool act0 = l0 <= q0w + 15;
    bool act1 = l0 <= q0w + 31;
    if (act1) {
      const u16* Kc = Ks[cur];
      const u16* Vc = Vs[cur];
      f32x4 st[2][4] = {};
      #pragma unroll
      for (int ls = 0; ls < 4; ls++) {
        short8 kf[4];
        #pragma unroll
        for (int kk = 0; kk < 4; kk++)
          kf[kk] = *(const short8a*)&Kc[(ls * 16 + lr) * 128 + ((kk * 32 + kg * 8) ^ sw)];
        #pragma unroll
        for (int kk = 0; kk < 4; kk++) {
          st[0][ls] = __builtin_amdgcn_mfma_f32_16x16x32_bf16(kf[kk], qf[0][kk], st[0][ls], 0, 0, 0);
          st[1][ls] = __builtin_amdgcn_mfma_f32_16x16x32_bf16(kf[kk], qf[1][kk], st[1][ls], 0, 0, 0);
        }
      }
      #pragma unroll
      for (int m = 0; m < 2; m++) {
        bool act = m ? act1 : act0;
        if (!act) continue;
        int qrow = q0w + m * 16 + lr;
        if (l0 + 63 > q0w + m * 16) {
          #pragma unroll
          for (int ls = 0; ls < 4; ls++)
            #pragma unroll
            for (int rr = 0; rr < 4; rr++) {
              int l = l0 + ls * 16 + kg * 4 + rr;
              st[m][ls][rr] = (l <= qrow) ? st[m][ls][rr] : -1e30f;
            }
        }
        float rmax;
        {
          float a0 = fmaxf(fmaxf(st[m][0][0], st[m][0][1]), fmaxf(st[m][0][2], st[m][0][3]));
          float a1 = fmaxf(fmaxf(st[m][1][0], st[m][1][1]), fmaxf(st[m][1][2], st[m][1][3]));
          float a2 = fmaxf(fmaxf(st[m][2][0], st[m][2][1]), fmaxf(st[m][2][2], st[m][2][3]));
          float a3 = fmaxf(fmaxf(st[m][3][0], st[m][3][1]), fmaxf(st[m][3][2], st[m][3][3]));
          rmax = fmaxf(fmaxf(a0, a1), fmaxf(a2, a3));
        }
        rmax = fmaxf(rmax, __shfl_xor(rmax, 16, 64));
        rmax = fmaxf(rmax, __shfl_xor(rmax, 32, 64));
        if (__any(rmax > mreg[m] + 8.0f)) {
          float nm = fmaxf(mreg[m], rmax);
          float f = __builtin_amdgcn_exp2f(mreg[m] - nm);
          mreg[m] = nm;
          lsum[m] *= f;
          float fr0 = __shfl(f, kg * 4 + 0, 64);
          float fr1 = __shfl(f, kg * 4 + 1, 64);
          float fr2 = __shfl(f, kg * 4 + 2, 64);
          float fr3 = __shfl(f, kg * 4 + 3, 64);
          #pragma unroll
          for (int dc = 0; dc < 8; dc++) {
            acc[m][dc][0] *= fr0; acc[m][dc][1] *= fr1;
            acc[m][dc][2] *= fr2; acc[m][dc][3] *= fr3;
          }
        }
        float e[4][4];
        #pragma unroll
        for (int ls = 0; ls < 4; ls++)
          #pragma unroll
          for (int rr = 0; rr < 4; rr++)
            e[ls][rr] = __builtin_amdgcn_exp2f(st[m][ls][rr] - mreg[m]);
        float rs = 0.f;
        #pragma unroll
        for (int ls = 0; ls < 4; ls++)
          rs += (e[ls][0] + e[ls][1]) + (e[ls][2] + e[ls][3]);
        rs += __shfl_xor(rs, 16, 64);
        rs += __shfl_xor(rs, 32, 64);
        lsum[m] += rs;
        u16* Pw = &Pl[wid][m][0];
        #pragma unroll
        for (int ls = 0; ls < 4; ls++) {
          __hip_bfloat162 p01 = __float22bfloat162_rn(float2{e[ls][0], e[ls][1]});
          __hip_bfloat162 p23 = __float22bfloat162_rn(float2{e[ls][2], e[ls][3]});
          uint2 pk;
          pk.x = *(u32*)&p01;
          pk.y = *(u32*)&p23;
          *(uint2*)&Pw[lr * 64 + ((ls * 16 + kg * 4) ^ sw)] = pk;
        }
      }
      #pragma unroll
      for (int kk = 0; kk < 2; kk++) {
        short8 pf0 = {}, pf1;
        if (act0) pf0 = *(const short8a*)&Pl[wid][0][lr * 64 + ((kk * 32 + kg * 8) ^ sw)];
        pf1 = *(const short8a*)&Pl[wid][1][lr * 64 + ((kk * 32 + kg * 8) ^ sw)];
        #pragma unroll
        for (int dc = 0; dc < 8; dc++) {
          short8 vf = *(const short8a*)&Vc[(dc * 16 + lr) * 64 + ((kk * 32 + kg * 8) ^ sw)];
          if (act0) acc[0][dc] = __builtin_amdgcn_mfma_f32_16x16x32_bf16(pf0, vf, acc[0][dc], 0, 0, 0);
          acc[1][dc] = __builtin_amdgcn_mfma_f32_16x16x32_bf16(pf1, vf, acc[1][dc], 0, 0, 0);
        }
      }
    }
    cur ^= 1;
  }
  #pragma unroll
  for (int m = 0; m < 2; m++) {
    float inv0 = 1.0f / __shfl(lsum[m], kg * 4 + 0, 64);
    float inv1 = 1.0f / __shfl(lsum[m], kg * 4 + 1, 64);
    float inv2 = 1.0f / __shfl(lsum[m], kg * 4 + 2, 64);
    float inv3 = 1.0f / __shfl(lsum[m], kg * 4 + 3, 64);
    #pragma unroll
    for (int dc = 0; dc < 8; dc++) {
      int col = h * D_ + dc * 16 + lr;
      int qg = q0w + m * 16 + kg * 4;
      Ot[(size_t)(qg + 0) * HID_ + col] = f2bf(acc[m][dc][0] * inv0);
      Ot[(size_t)(qg + 1) * HID_ + col] = f2bf(acc[m][dc][1] * inv1);
      Ot[(size_t)(qg + 2) * HID_ + col] = f2bf(acc[m][dc][2] * inv2);
      Ot[(size_t)(qg + 3) * HID_ + col] = f2bf(acc[m][dc][3] * inv3);
    }
  }
}

// ---------------- workspace layout (bytes) ----------------
static constexpr size_t OFF_WQKV = 0;           // 50331648 (6144x4096 bf16); reused post-QKV-gemm
static constexpr size_t OFF_WO   = 50331648;    // 33554432 (4096x4096 bf16)
static constexpr size_t OFF_XT   = 83886080;    // 16777216 (2048x4096 bf16)
static constexpr size_t OFF_QKVC = 100663296;   // 25165824 -> total 125829120

// log2(e)/sqrt(128): folds softmax scale + base-2 exp into Q
#define QSCALE 0.1275176329533421f

extern "C" void kernel_launch(void* const* d_in, const int* in_sizes, int n_in,
                              void* d_out, int out_size, void* d_ws, size_t ws_size,
                              hipStream_t stream) {
  const float* x    = (const float*)d_in[0];
  const float* wq   = (const float*)d_in[1];
  const float* bq   = (const float*)d_in[2];
  const float* wk   = (const float*)d_in[3];
  const float* bk   = (const float*)d_in[4];
  const float* wv   = (const float*)d_in[5];
  const float* bv   = (const float*)d_in[6];
  const float* wo   = (const float*)d_in[7];
  const float* cosP = (const float*)d_in[8];
  const float* sinP = (const float*)d_in[9];
  char* ws = (char*)d_ws;
  u16* WQKV = (u16*)(ws + OFF_WQKV);
  u16* WO   = (u16*)(ws + OFF_WO);
  u16* XT   = (u16*)(ws + OFF_XT);
  u16* QKVC = (u16*)(ws + OFF_QKVC);
  u16* QT   = QKVC;
  u16* KT   = QKVC + (size_t)4096 * S_;
  u16* VB   = QKVC + (size_t)5120 * S_;
  u16* QATT = (u16*)(ws + 0);
  u16* KATT = (u16*)(ws + 16777216);
  u16* OT   = (u16*)(ws + 20971520);
  float* y = (float*)d_out;

  // 1) fused weight casts
  cast4_kernel<<<2048, 256, 0, stream>>>(
      wq, wk, wv, wo,
      WQKV, WQKV + (size_t)4096 * HID_, WQKV + (size_t)5120 * HID_, WO,
      (HID_ * HID_) / 4, (KV_ * D_ * HID_) / 4, (KV_ * D_ * HID_) / 4, (HID_ * HID_) / 4);
  // 2) X^T
  transpose_cast_kernel<<<dim3(S_ / 32, HID_ / 32), 256, 0, stream>>>(x, XT);
  // 3) fused QKV projection (M=6144), BM=192 round-6 schedule, 256 blocks
  gemm_t<192><<<dim3(S_ / 256, 6144 / 192), 512, 0, stream>>>(WQKV, XT, bq, bk, bv,
                                                              QKVC, nullptr, S_, HID_);
  // 4) RoPE + transpose
  rope_transpose_kernel<<<dim3(H_, S_ / 32), 256, 0, stream>>>(QT, QATT, cosP, sinP, QSCALE);
  rope_transpose_kernel<<<dim3(KV_, S_ / 32), 256, 0, stream>>>(KT, KATT, cosP, sinP, 1.0f);
  // 5) causal GQA flash attention -> O^T (S, H*D)
  attn_v2<<<dim3(H_, S_ / 128), 256, 0, stream>>>(QATT, KATT, VB, OT);
  // 6) output projection: 128x128, 4-wave, 2 blocks/CU (512 blocks) -> fp32 d_out
  gemm128<<<dim3(S_ / 128, HID_ / 128), 256, 0, stream>>>(WO, OT, y, S_, HID_);
}

// Round 9
// 349.839 us; speedup vs baseline: 1.1219x; 1.0491x over previous
//
#include <hip/hip_runtime.h>
#include <hip/hip_bf16.h>

// Problem constants
#define H_   32
#define KV_  8
#define D_   128
#define S_   2048
#define HID_ 4096

typedef __attribute__((ext_vector_type(8))) short short8;
typedef short8 short8a __attribute__((may_alias));
typedef __attribute__((ext_vector_type(4))) float f32x4;
typedef unsigned short u16;
typedef unsigned int u32;

__device__ __forceinline__ u16 f2bf(float f) {
  union { float f; unsigned u; } a; a.f = f;
  unsigned r = a.u + 0x7fffu + ((a.u >> 16) & 1u);   // RNE
  return (u16)(r >> 16);
}
__device__ __forceinline__ float bf2f(u16 h) {
  union { unsigned u; float f; } a; a.u = ((unsigned)h) << 16;
  return a.f;
}

#define GLOAD16(g, l) __builtin_amdgcn_global_load_lds( \
    (const __attribute__((address_space(1))) void*)(g), \
    (__attribute__((address_space(3))) void*)(l), 16, 0, 0)

// ---------------- fused fp32 -> bf16 cast of all 4 weights ----------------
__global__ void cast4_kernel(const float* __restrict__ s0, const float* __restrict__ s1,
                             const float* __restrict__ s2, const float* __restrict__ s3,
                             u16* __restrict__ d0, u16* __restrict__ d1,
                             u16* __restrict__ d2, u16* __restrict__ d3,
                             int n0, int n1, int n2, int n3) {
  int total = n0 + n1 + n2 + n3;
  for (int i = blockIdx.x * blockDim.x + threadIdx.x; i < total; i += gridDim.x * blockDim.x) {
    const float* s; u16* d; int k = i;
    if (k < n0) { s = s0; d = d0; }
    else if ((k -= n0) < n1) { s = s1; d = d1; }
    else if ((k -= n1) < n2) { s = s2; d = d2; }
    else { k -= n2; s = s3; d = d3; }
    float4 v = ((const float4*)s)[k];
    ushort4 o;
    o.x = f2bf(v.x); o.y = f2bf(v.y); o.z = f2bf(v.z); o.w = f2bf(v.w);
    ((ushort4*)d)[k] = o;
  }
}

// ---------------- X (HID,S) fp32 -> X^T (S,HID) bf16 ----------------
__global__ __launch_bounds__(256) void transpose_cast_kernel(const float* __restrict__ in,
                                                             u16* __restrict__ out) {
  __shared__ float t[32][33];
  int tx = threadIdx.x & 31, ty = threadIdx.x >> 5;  // 32x8
  int s0 = blockIdx.x * 32, c0 = blockIdx.y * 32;
  #pragma unroll
  for (int i = 0; i < 4; i++)
    t[ty + i * 8][tx] = in[(size_t)(c0 + ty + i * 8) * S_ + s0 + tx];
  __syncthreads();
  #pragma unroll
  for (int i = 0; i < 4; i++)
    out[(size_t)(s0 + ty + i * 8) * HID_ + c0 + tx] = f2bf(t[tx][ty + i * 8]);
}

__device__ __forceinline__ short8 ldsfrag(const u16* base, int row, int ks, int kg) {
  int cb = (ks * 64 + kg * 16) ^ ((row & 7) << 4);
  return *(const short8a*)((const char*)base + row * 128 + cb);
}

// ---------------- BM x 256 bf16 GEMM (round-6 proven schedule, 8 waves) ----------------
template<int BM>
__global__ __launch_bounds__(512, 2) void gemm_t(const u16* __restrict__ A, const u16* __restrict__ Bt,
    const float* __restrict__ bq, const float* __restrict__ bk, const float* __restrict__ bv,
    u16* __restrict__ Cb, float* __restrict__ Cf, int N, int K) {
  constexpr int CA = BM / 64;
  constexpr int CA1 = (CA + 1) / 2;
  constexpr int MI = BM / 64;
  __shared__ alignas(16) u16 Asl[2][BM * 64];
  __shared__ alignas(16) u16 Bsl[2][256 * 64];
  int tid = threadIdx.x, wid = tid >> 6, lane = tid & 63;
  int lr = lane & 15, kg = lane >> 4;
  int gx = gridDim.x, nwg = gx * gridDim.y;
  int lid = blockIdx.y * gx + blockIdx.x;
  int q = nwg >> 3, r = nwg & 7;
  int xcd = lid & 7, idx = lid >> 3;
  int swz = (xcd < r ? xcd * (q + 1) : r * (q + 1) + (xcd - r) * q) + idx;
  int m0 = (swz / gx) * BM, n0 = (swz % gx) * 256;
  const u16* Ap = A + (size_t)m0 * K;
  const u16* Bp = Bt + (size_t)n0 * K;
  int wm = wid >> 2, wn = wid & 3;
  f32x4 acc[2][2][MI][2] = {};
  int NT = K >> 6;

  auto STAGEC = [&](const u16* gp, int tile, int chunk, u16* base) {
    int p = tid * 16;
    int row = (chunk << 6) + (p >> 7);
    int gcb = (p & 127) ^ ((row & 7) << 4);
    const char* src = (const char*)gp + ((size_t)row * K + (tile << 6)) * 2 + gcb;
    char* dst = (char*)base + (chunk << 13) + (wid << 10);
    GLOAD16(src, dst);
  };
  auto LDA = [&](short8 (&af)[MI][2], const u16* base, int qm) {
    #pragma unroll
    for (int mi = 0; mi < MI; mi++)
      #pragma unroll
      for (int ks = 0; ks < 2; ks++)
        af[mi][ks] = ldsfrag(base, wm * (BM / 2) + qm * (BM / 4) + mi * 16 + lr, ks, kg);
  };
  auto LDB = [&](short8 (&bf)[2][2], const u16* base, int qn) {
    #pragma unroll
    for (int ni = 0; ni < 2; ni++)
      #pragma unroll
      for (int ks = 0; ks < 2; ks++)
        bf[ni][ks] = ldsfrag(base, wn * 64 + qn * 32 + ni * 16 + lr, ks, kg);
  };
  auto MM = [&](f32x4 (&a)[MI][2], short8 (&af)[MI][2], short8 (&bf)[2][2]) {
    __builtin_amdgcn_s_setprio(1);
    #pragma unroll
    for (int ks = 0; ks < 2; ks++)
      #pragma unroll
      for (int mi = 0; mi < MI; mi++)
        #pragma unroll
        for (int ni = 0; ni < 2; ni++)
          a[mi][ni] = __builtin_amdgcn_mfma_f32_16x16x32_bf16(af[mi][ks], bf[ni][ks], a[mi][ni], 0, 0, 0);
    __builtin_amdgcn_s_setprio(0);
  };
  #define BAR() __builtin_amdgcn_s_barrier()
  #define SB()  __builtin_amdgcn_sched_barrier(0)
  #define VMCNT(n) asm volatile("s_waitcnt vmcnt(" #n ")" ::: "memory")

  #pragma unroll
  for (int c = 0; c < CA; c++) STAGEC(Ap, 0, c, &Asl[0][0]);
  #pragma unroll
  for (int c = 0; c < 4; c++) STAGEC(Bp, 0, c, &Bsl[0][0]);
  #pragma unroll
  for (int c = 0; c < 4; c++) STAGEC(Bp, 1, c, &Bsl[1][0]);
  VMCNT(4);
  BAR();

  short8 af[MI][2], bfA[2][2], bfB[2][2];
  for (int T = 0; T < NT; T++) {
    int par = T & 1;
    u16* aC = &Asl[par][0];
    u16* bC = &Bsl[par][0];
    u16* aN = &Asl[par ^ 1][0];
    int tA = T + 1 < NT ? T + 1 : NT - 1;
    int tB = T + 2 < NT ? T + 2 : NT - 1;
    LDA(af, aC, 0); LDB(bfA, bC, 0);
    #pragma unroll
    for (int c = 0; c < CA1; c++) STAGEC(Ap, tA, c, aN);
    SB(); BAR();
    MM(acc[0][0], af, bfA);
    BAR();
    LDB(bfB, bC, 1);
    #pragma unroll
    for (int c = CA1; c < CA; c++) STAGEC(Ap, tA, c, aN);
    SB(); BAR();
    MM(acc[0][1], af, bfB);
    BAR();
    LDA(af, aC, 1);
    STAGEC(Bp, tB, 0, bC); STAGEC(Bp, tB, 1, bC);
    SB(); BAR();
    MM(acc[1][0], af, bfA);
    BAR();
    STAGEC(Bp, tB, 2, bC); STAGEC(Bp, tB, 3, bC);
    VMCNT(4);
    SB(); BAR();
    MM(acc[1][1], af, bfB);
    BAR();
  }
  #undef BAR
  #undef SB
  #undef VMCNT

  #pragma unroll
  for (int qm = 0; qm < 2; qm++)
    #pragma unroll
    for (int qn = 0; qn < 2; qn++)
      #pragma unroll
      for (int mi = 0; mi < MI; mi++)
        #pragma unroll
        for (int ni = 0; ni < 2; ni++) {
          int col = n0 + wn * 64 + qn * 32 + ni * 16 + lr;
          int rbase = m0 + wm * (BM / 2) + qm * (BM / 4) + mi * 16 + kg * 4;
          #pragma unroll
          for (int rr = 0; rr < 4; rr++) {
            int row = rbase + rr;
            float v = acc[qm][qn][mi][ni][rr];
            if (bq) v += row < 4096 ? bq[row] : (row < 5120 ? bk[row - 4096] : bv[row - 5120]);
            if (Cf) Cf[(size_t)row * N + col] = v;
            else    Cb[(size_t)row * N + col] = f2bf(v);
          }
        }
}

// ---------------- 128x128 bf16 GEMM, 4 waves, 2 blocks/CU, 2-phase (16-MFMA clusters) ----------------
// v2: all 16 fragment reads in ph1, 4 barriers/tile (was 8). Hazards:
//  - ph2 stage B(T+2)->bC issued after ph1-end BAR: all waves' bC ds_reads completed
//    (each wave's reads drain via lgkm before its MM, which precedes ph1-end BAR).
//  - per-thread vmcnt(4) after B-stage drains A(T+1)+older B => tile T+1 fully landed.
__global__ __launch_bounds__(256, 2) void gemm128(const u16* __restrict__ A, const u16* __restrict__ Bt,
                                                  float* __restrict__ Cf, int N, int K) {
  __shared__ alignas(16) u16 Asl[2][128 * 64];
  __shared__ alignas(16) u16 Bsl[2][128 * 64];
  int tid = threadIdx.x, wid = tid >> 6, lane = tid & 63;
  int lr = lane & 15, kg = lane >> 4;
  int gx = gridDim.x, nwg = gx * gridDim.y;
  int lid = blockIdx.y * gx + blockIdx.x;
  int q = nwg >> 3, r = nwg & 7;
  int xcd = lid & 7, idx = lid >> 3;
  int swz = (xcd < r ? xcd * (q + 1) : r * (q + 1) + (xcd - r) * q) + idx;
  int m0 = (swz / gx) * 128, n0 = (swz % gx) * 128;
  const u16* Ap = A + (size_t)m0 * K;
  const u16* Bp = Bt + (size_t)n0 * K;
  int wr = wid >> 1, wc = wid & 1;   // 2x2 waves, wave tile 64x64
  f32x4 acc[2][2][2][2] = {};        // [qm][qn][mi][ni]
  int NT = K >> 6;

  auto STAGEC = [&](const u16* gp, int tile, int chunk, u16* base) {
    int p = (chunk << 12) + tid * 16;        // 4KB chunks (32 rows), 256 threads
    int row = p >> 7;
    int gcb = (p & 127) ^ ((row & 7) << 4);
    const char* src = (const char*)gp + ((size_t)row * K + (tile << 6)) * 2 + gcb;
    char* dst = (char*)base + (chunk << 12) + (wid << 10);
    GLOAD16(src, dst);
  };
  auto LDA = [&](short8 (&af)[2][2], const u16* base, int qm) {
    #pragma unroll
    for (int mi = 0; mi < 2; mi++)
      #pragma unroll
      for (int ks = 0; ks < 2; ks++)
        af[mi][ks] = ldsfrag(base, wr * 64 + qm * 32 + mi * 16 + lr, ks, kg);
  };
  auto LDB = [&](short8 (&bf)[2][2], const u16* base, int qn) {
    #pragma unroll
    for (int ni = 0; ni < 2; ni++)
      #pragma unroll
      for (int ks = 0; ks < 2; ks++)
        bf[ni][ks] = ldsfrag(base, wc * 64 + qn * 32 + ni * 16 + lr, ks, kg);
  };
  auto MM = [&](f32x4 (&a)[2][2], short8 (&af)[2][2], short8 (&bf)[2][2]) {
    #pragma unroll
    for (int ks = 0; ks < 2; ks++)
      #pragma unroll
      for (int mi = 0; mi < 2; mi++)
        #pragma unroll
        for (int ni = 0; ni < 2; ni++)
          a[mi][ni] = __builtin_amdgcn_mfma_f32_16x16x32_bf16(af[mi][ks], bf[ni][ks], a[mi][ni], 0, 0, 0);
  };
  #define BAR() __builtin_amdgcn_s_barrier()
  #define SB()  __builtin_amdgcn_sched_barrier(0)
  #define VMCNT(n) asm volatile("s_waitcnt vmcnt(" #n ")" ::: "memory")

  // prologue: A0(4), B0(4), B1(4); drain to B1-in-flight
  #pragma unroll
  for (int c = 0; c < 4; c++) STAGEC(Ap, 0, c, &Asl[0][0]);
  #pragma unroll
  for (int c = 0; c < 4; c++) STAGEC(Bp, 0, c, &Bsl[0][0]);
  #pragma unroll
  for (int c = 0; c < 4; c++) STAGEC(Bp, 1, c, &Bsl[1][0]);
  VMCNT(4);
  BAR();

  short8 af0[2][2], af1[2][2], bfA[2][2], bfB[2][2];
  for (int T = 0; T < NT; T++) {
    int par = T & 1;
    u16* aC = &Asl[par][0];
    u16* bC = &Bsl[par][0];
    u16* aN = &Asl[par ^ 1][0];
    int tA = T + 1 < NT ? T + 1 : NT - 1;
    int tB = T + 2 < NT ? T + 2 : NT - 1;
    // ph1: all 16 fragment reads + stage A(T+1); 16-MFMA cluster (qm=0)
    LDA(af0, aC, 0); LDA(af1, aC, 1); LDB(bfA, bC, 0); LDB(bfB, bC, 1);
    STAGEC(Ap, tA, 0, aN); STAGEC(Ap, tA, 1, aN);
    STAGEC(Ap, tA, 2, aN); STAGEC(Ap, tA, 3, aN);
    SB(); BAR();
    __builtin_amdgcn_s_setprio(1);
    MM(acc[0][0], af0, bfA); MM(acc[0][1], af0, bfB);
    __builtin_amdgcn_s_setprio(0);
    BAR();
    // ph2: stage B(T+2); vmcnt(4) -> T+1 fully landed; 16-MFMA cluster (qm=1)
    STAGEC(Bp, tB, 0, bC); STAGEC(Bp, tB, 1, bC);
    STAGEC(Bp, tB, 2, bC); STAGEC(Bp, tB, 3, bC);
    VMCNT(4);
    SB(); BAR();
    __builtin_amdgcn_s_setprio(1);
    MM(acc[1][0], af1, bfA); MM(acc[1][1], af1, bfB);
    __builtin_amdgcn_s_setprio(0);
    BAR();
  }
  #undef BAR
  #undef SB
  #undef VMCNT

  #pragma unroll
  for (int qm = 0; qm < 2; qm++)
    #pragma unroll
    for (int qn = 0; qn < 2; qn++)
      #pragma unroll
      for (int mi = 0; mi < 2; mi++)
        #pragma unroll
        for (int ni = 0; ni < 2; ni++) {
          int col = n0 + wc * 64 + qn * 32 + ni * 16 + lr;
          int rbase = m0 + wr * 64 + qm * 32 + mi * 16 + kg * 4;
          #pragma unroll
          for (int rr = 0; rr < 4; rr++)
            Cf[(size_t)(rbase + rr) * N + col] = acc[qm][qn][mi][ni][rr];
        }
}

// ---------------- RoPE + transpose (Q and K heads in one launch) ----------------
// in layout (nH*D, S) bf16 -> out (nH, S, D) bf16; blockIdx.x < H_ => Q (scaled), else K.
__global__ __launch_bounds__(256) void rope2_kernel(const u16* __restrict__ qin,
                                                    const u16* __restrict__ kin,
                                                    u16* __restrict__ qout,
                                                    u16* __restrict__ kout,
                                                    const float* __restrict__ cp,
                                                    const float* __restrict__ sp) {
  __shared__ u16 t[128][33];
  int hh = blockIdx.x;
  bool isQ = hh < H_;
  int h = isQ ? hh : hh - H_;
  const u16* in = (isQ ? qin : kin) + (size_t)h * 128 * S_;
  u16* out = (isQ ? qout : kout) + (size_t)h * S_ * D_;
  float oscale = isQ ? 0.1275176329533421f : 1.0f;   // log2(e)/sqrt(128) folded into Q
  int s0 = blockIdx.y * 32;
  int tid = threadIdx.x;
  #pragma unroll
  for (int i = 0; i < 16; i++) {
    int idx = tid + i * 256;
    int row = idx >> 5, sc = idx & 31;
    t[row][sc] = in[(size_t)row * S_ + s0 + sc];
  }
  __syncthreads();
  int d = tid & 127, sh = tid >> 7;
  int dl = d & 63;
  bool hi = d >= 64;
  #pragma unroll
  for (int j = 0; j < 16; j++) {
    int sl = sh * 16 + j;
    int s = s0 + sl;
    float x = bf2f(t[d][sl]);
    float p = bf2f(t[d ^ 64][sl]);
    float c  = cp[(size_t)s * D_ + dl];
    float sn = sp[(size_t)s * D_ + dl];
    float o = hi ? fmaf(p, sn, x * c) : fmaf(-p, sn, x * c);
    out[(size_t)s * D_ + d] = f2bf(o * oscale);
  }
}

// ---------------- flash attention v2 (causal GQA, swapped-QK, staged KV) ----------------
__global__ __launch_bounds__(256) void attn_v2(const u16* __restrict__ Q, const u16* __restrict__ K,
                                               const u16* __restrict__ V, u16* __restrict__ Ot) {
  __shared__ alignas(16) u16 Ks[2][64 * 128];
  __shared__ alignas(16) u16 Vs[2][128 * 64];
  __shared__ alignas(16) u16 Pl[4][2][16 * 64];
  int h = blockIdx.x;
  int qtile = (int)(gridDim.y - 1) - (int)blockIdx.y;   // heavy first
  int kv = h >> 2;
  int tid = threadIdx.x, wid = tid >> 6, lane = tid & 63;
  int lr = lane & 15, kg = lane >> 4;
  int q0w = qtile * 128 + wid * 32;
  const u16* Qb = Q + ((size_t)h * S_ + q0w) * D_;
  const u16* Kb = K + (size_t)kv * S_ * D_;
  const u16* Vb = V + (size_t)kv * D_ * S_;
  int sw = (lr & 7) << 3;

  short8 qf[2][4];
  #pragma unroll
  for (int m = 0; m < 2; m++)
    #pragma unroll
    for (int kk = 0; kk < 4; kk++)
      qf[m][kk] = *(const short8a*)(Qb + (size_t)(m * 16 + lr) * D_ + kk * 32 + kg * 8);

  f32x4 acc[2][8] = {};
  float mreg[2] = {-1e30f, -1e30f};
  float lsum[2] = {0.f, 0.f};

  int krow[4], kcb[4], vrow[4], vcb[4];
  #pragma unroll
  for (int j = 0; j < 4; j++) {
    int c = wid * 4 + j;
    int o = c * 1024 + lane * 16;
    krow[j] = o >> 8;
    kcb[j] = (o & 255) ^ ((krow[j] & 7) << 4);
    vrow[j] = o >> 7;
    vcb[j] = (o & 127) ^ ((vrow[j] & 7) << 4);
  }

  int nlt = 2 * qtile + 2;
  #pragma unroll
  for (int j = 0; j < 4; j++) {
    int c = wid * 4 + j;
    GLOAD16((const char*)Kb + ((size_t)krow[j] * D_) * 2 + kcb[j], (char*)Ks[0] + c * 1024);
    GLOAD16((const char*)Vb + ((size_t)vrow[j] * S_) * 2 + vcb[j], (char*)Vs[0] + c * 1024);
  }
  int cur = 0;
  for (int t = 0; t < nlt; t++) {
    __syncthreads();
    if (t + 1 < nlt) {
      int l1 = (t + 1) * 64;
      #pragma unroll
      for (int j = 0; j < 4; j++) {
        int c = wid * 4 + j;
        GLOAD16((const char*)Kb + ((size_t)(l1 + krow[j]) * D_) * 2 + kcb[j],
                (char*)Ks[cur ^ 1] + c * 1024);
        GLOAD16((const char*)Vb + ((size_t)vrow[j] * S_ + l1) * 2 + vcb[j],
                (char*)Vs[cur ^ 1] + c * 1024);
      }
    }
    int l0 = t * 64;
    bool act0 = l0 <= q0w + 15;
    bool act1 = l0 <= q0w + 31;
    if (act1) {
      const u16* Kc = Ks[cur];
      const u16* Vc = Vs[cur];
      f32x4 st[2][4] = {};
      #pragma unroll
      for (int ls = 0; ls < 4; ls++) {
        short8 kf[4];
        #pragma unroll
        for (int kk = 0; kk < 4; kk++)
          kf[kk] = *(const short8a*)&Kc[(ls * 16 + lr) * 128 + ((kk * 32 + kg * 8) ^ sw)];
        #pragma unroll
        for (int kk = 0; kk < 4; kk++) {
          st[0][ls] = __builtin_amdgcn_mfma_f32_16x16x32_bf16(kf[kk], qf[0][kk], st[0][ls], 0, 0, 0);
          st[1][ls] = __builtin_amdgcn_mfma_f32_16x16x32_bf16(kf[kk], qf[1][kk], st[1][ls], 0, 0, 0);
        }
      }
      #pragma unroll
      for (int m = 0; m < 2; m++) {
        bool act = m ? act1 : act0;
        if (!act) continue;
        int qrow = q0w + m * 16 + lr;
        if (l0 + 63 > q0w + m * 16) {
          #pragma unroll
          for (int ls = 0; ls < 4; ls++)
            #pragma unroll
            for (int rr = 0; rr < 4; rr++) {
              int l = l0 + ls * 16 + kg * 4 + rr;
              st[m][ls][rr] = (l <= qrow) ? st[m][ls][rr] : -1e30f;
            }
        }
        float rmax;
        {
          float a0 = fmaxf(fmaxf(st[m][0][0], st[m][0][1]), fmaxf(st[m][0][2], st[m][0][3]));
          float a1 = fmaxf(fmaxf(st[m][1][0], st[m][1][1]), fmaxf(st[m][1][2], st[m][1][3]));
          float a2 = fmaxf(fmaxf(st[m][2][0], st[m][2][1]), fmaxf(st[m][2][2], st[m][2][3]));
          float a3 = fmaxf(fmaxf(st[m][3][0], st[m][3][1]), fmaxf(st[m][3][2], st[m][3][3]));
          rmax = fmaxf(fmaxf(a0, a1), fmaxf(a2, a3));
        }
        rmax = fmaxf(rmax, __shfl_xor(rmax, 16, 64));
        rmax = fmaxf(rmax, __shfl_xor(rmax, 32, 64));
        if (__any(rmax > mreg[m] + 8.0f)) {
          float nm = fmaxf(mreg[m], rmax);
          float f = __builtin_amdgcn_exp2f(mreg[m] - nm);
          mreg[m] = nm;
          lsum[m] *= f;
          float fr0 = __shfl(f, kg * 4 + 0, 64);
          float fr1 = __shfl(f, kg * 4 + 1, 64);
          float fr2 = __shfl(f, kg * 4 + 2, 64);
          float fr3 = __shfl(f, kg * 4 + 3, 64);
          #pragma unroll
          for (int dc = 0; dc < 8; dc++) {
            acc[m][dc][0] *= fr0; acc[m][dc][1] *= fr1;
            acc[m][dc][2] *= fr2; acc[m][dc][3] *= fr3;
          }
        }
        float e[4][4];
        #pragma unroll
        for (int ls = 0; ls < 4; ls++)
          #pragma unroll
          for (int rr = 0; rr < 4; rr++)
            e[ls][rr] = __builtin_amdgcn_exp2f(st[m][ls][rr] - mreg[m]);
        float rs = 0.f;
        #pragma unroll
        for (int ls = 0; ls < 4; ls++)
          rs += (e[ls][0] + e[ls][1]) + (e[ls][2] + e[ls][3]);
        rs += __shfl_xor(rs, 16, 64);
        rs += __shfl_xor(rs, 32, 64);
        lsum[m] += rs;
        u16* Pw = &Pl[wid][m][0];
        #pragma unroll
        for (int ls = 0; ls < 4; ls++) {
          __hip_bfloat162 p01 = __float22bfloat162_rn(float2{e[ls][0], e[ls][1]});
          __hip_bfloat162 p23 = __float22bfloat162_rn(float2{e[ls][2], e[ls][3]});
          uint2 pk;
          pk.x = *(u32*)&p01;
          pk.y = *(u32*)&p23;
          *(uint2*)&Pw[lr * 64 + ((ls * 16 + kg * 4) ^ sw)] = pk;
        }
      }
      #pragma unroll
      for (int kk = 0; kk < 2; kk++) {
        short8 pf0 = {}, pf1;
        if (act0) pf0 = *(const short8a*)&Pl[wid][0][lr * 64 + ((kk * 32 + kg * 8) ^ sw)];
        pf1 = *(const short8a*)&Pl[wid][1][lr * 64 + ((kk * 32 + kg * 8) ^ sw)];
        #pragma unroll
        for (int dc = 0; dc < 8; dc++) {
          short8 vf = *(const short8a*)&Vc[(dc * 16 + lr) * 64 + ((kk * 32 + kg * 8) ^ sw)];
          if (act0) acc[0][dc] = __builtin_amdgcn_mfma_f32_16x16x32_bf16(pf0, vf, acc[0][dc], 0, 0, 0);
          acc[1][dc] = __builtin_amdgcn_mfma_f32_16x16x32_bf16(pf1, vf, acc[1][dc], 0, 0, 0);
        }
      }
    }
    cur ^= 1;
  }
  #pragma unroll
  for (int m = 0; m < 2; m++) {
    float inv0 = 1.0f / __shfl(lsum[m], kg * 4 + 0, 64);
    float inv1 = 1.0f / __shfl(lsum[m], kg * 4 + 1, 64);
    float inv2 = 1.0f / __shfl(lsum[m], kg * 4 + 2, 64);
    float inv3 = 1.0f / __shfl(lsum[m], kg * 4 + 3, 64);
    #pragma unroll
    for (int dc = 0; dc < 8; dc++) {
      int col = h * D_ + dc * 16 + lr;
      int qg = q0w + m * 16 + kg * 4;
      Ot[(size_t)(qg + 0) * HID_ + col] = f2bf(acc[m][dc][0] * inv0);
      Ot[(size_t)(qg + 1) * HID_ + col] = f2bf(acc[m][dc][1] * inv1);
      Ot[(size_t)(qg + 2) * HID_ + col] = f2bf(acc[m][dc][2] * inv2);
      Ot[(size_t)(qg + 3) * HID_ + col] = f2bf(acc[m][dc][3] * inv3);
    }
  }
}

// ---------------- workspace layout (bytes) ----------------
static constexpr size_t OFF_WQKV = 0;           // 50331648 (6144x4096 bf16); reused post-QKV-gemm
static constexpr size_t OFF_WO   = 50331648;    // 33554432 (4096x4096 bf16)
static constexpr size_t OFF_XT   = 83886080;    // 16777216 (2048x4096 bf16)
static constexpr size_t OFF_QKVC = 100663296;   // 25165824 -> total 125829120

extern "C" void kernel_launch(void* const* d_in, const int* in_sizes, int n_in,
                              void* d_out, int out_size, void* d_ws, size_t ws_size,
                              hipStream_t stream) {
  const float* x    = (const float*)d_in[0];
  const float* wq   = (const float*)d_in[1];
  const float* bq   = (const float*)d_in[2];
  const float* wk   = (const float*)d_in[3];
  const float* bk   = (const float*)d_in[4];
  const float* wv   = (const float*)d_in[5];
  const float* bv   = (const float*)d_in[6];
  const float* wo   = (const float*)d_in[7];
  const float* cosP = (const float*)d_in[8];
  const float* sinP = (const float*)d_in[9];
  char* ws = (char*)d_ws;
  u16* WQKV = (u16*)(ws + OFF_WQKV);
  u16* WO   = (u16*)(ws + OFF_WO);
  u16* XT   = (u16*)(ws + OFF_XT);
  u16* QKVC = (u16*)(ws + OFF_QKVC);
  u16* QT   = QKVC;
  u16* KT   = QKVC + (size_t)4096 * S_;
  u16* VB   = QKVC + (size_t)5120 * S_;
  u16* QATT = (u16*)(ws + 0);
  u16* KATT = (u16*)(ws + 16777216);
  u16* OT   = (u16*)(ws + 20971520);
  float* y = (float*)d_out;

  // 1) fused weight casts
  cast4_kernel<<<2048, 256, 0, stream>>>(
      wq, wk, wv, wo,
      WQKV, WQKV + (size_t)4096 * HID_, WQKV + (size_t)5120 * HID_, WO,
      (HID_ * HID_) / 4, (KV_ * D_ * HID_) / 4, (KV_ * D_ * HID_) / 4, (HID_ * HID_) / 4);
  // 2) X^T
  transpose_cast_kernel<<<dim3(S_ / 32, HID_ / 32), 256, 0, stream>>>(x, XT);
  // 3) fused QKV projection (M=6144), BM=192 round-6 schedule, 256 blocks
  gemm_t<192><<<dim3(S_ / 256, 6144 / 192), 512, 0, stream>>>(WQKV, XT, bq, bk, bv,
                                                              QKVC, nullptr, S_, HID_);
  // 4) RoPE + transpose (Q scaled by log2e/sqrt(D)), one launch for Q+K heads
  rope2_kernel<<<dim3(H_ + KV_, S_ / 32), 256, 0, stream>>>(QT, KT, QATT, KATT, cosP, sinP);
  // 5) causal GQA flash attention -> O^T (S, H*D)
  attn_v2<<<dim3(H_, S_ / 128), 256, 0, stream>>>(QATT, KATT, VB, OT);
  // 6) output projection: 128x128, 4-wave, 2 blocks/CU, 2-phase schedule -> fp32 d_out
  gemm128<<<dim3(S_ / 128, HID_ / 128), 256, 0, stream>>>(WO, OT, y, S_, HID_);
}

// Round 10
// 333.664 us; speedup vs baseline: 1.1762x; 1.0485x over previous
//
#include <hip/hip_runtime.h>
#include <hip/hip_bf16.h>

// Problem constants
#define H_   32
#define KV_  8
#define D_   128
#define S_   2048
#define HID_ 4096

typedef __attribute__((ext_vector_type(8))) short short8;
typedef short8 short8a __attribute__((may_alias));
typedef __attribute__((ext_vector_type(4))) float f32x4;
typedef unsigned short u16;
typedef unsigned int u32;

__device__ __forceinline__ u16 f2bf(float f) {
  union { float f; unsigned u; } a; a.f = f;
  unsigned r = a.u + 0x7fffu + ((a.u >> 16) & 1u);   // RNE
  return (u16)(r >> 16);
}
__device__ __forceinline__ float bf2f(u16 h) {
  union { unsigned u; float f; } a; a.u = ((unsigned)h) << 16;
  return a.f;
}

#define GLOAD16(g, l) __builtin_amdgcn_global_load_lds( \
    (const __attribute__((address_space(1))) void*)(g), \
    (__attribute__((address_space(3))) void*)(l), 16, 0, 0)

// ---------------- fused fp32 -> bf16 cast of all 4 weights ----------------
__global__ void cast4_kernel(const float* __restrict__ s0, const float* __restrict__ s1,
                             const float* __restrict__ s2, const float* __restrict__ s3,
                             u16* __restrict__ d0, u16* __restrict__ d1,
                             u16* __restrict__ d2, u16* __restrict__ d3,
                             int n0, int n1, int n2, int n3) {
  int total = n0 + n1 + n2 + n3;
  for (int i = blockIdx.x * blockDim.x + threadIdx.x; i < total; i += gridDim.x * blockDim.x) {
    const float* s; u16* d; int k = i;
    if (k < n0) { s = s0; d = d0; }
    else if ((k -= n0) < n1) { s = s1; d = d1; }
    else if ((k -= n1) < n2) { s = s2; d = d2; }
    else { k -= n2; s = s3; d = d3; }
    float4 v = ((const float4*)s)[k];
    ushort4 o;
    o.x = f2bf(v.x); o.y = f2bf(v.y); o.z = f2bf(v.z); o.w = f2bf(v.w);
    ((ushort4*)d)[k] = o;
  }
}

// ---------------- X (HID,S) fp32 -> X^T (S,HID) bf16 ----------------
__global__ __launch_bounds__(256) void transpose_cast_kernel(const float* __restrict__ in,
                                                             u16* __restrict__ out) {
  __shared__ float t[32][33];
  int tx = threadIdx.x & 31, ty = threadIdx.x >> 5;  // 32x8
  int s0 = blockIdx.x * 32, c0 = blockIdx.y * 32;
  #pragma unroll
  for (int i = 0; i < 4; i++)
    t[ty + i * 8][tx] = in[(size_t)(c0 + ty + i * 8) * S_ + s0 + tx];
  __syncthreads();
  #pragma unroll
  for (int i = 0; i < 4; i++)
    out[(size_t)(s0 + ty + i * 8) * HID_ + c0 + tx] = f2bf(t[tx][ty + i * 8]);
}

__device__ __forceinline__ short8 ldsfrag(const u16* base, int row, int ks, int kg) {
  int cb = (ks * 64 + kg * 16) ^ ((row & 7) << 4);
  return *(const short8a*)((const char*)base + row * 128 + cb);
}

// ---------------- BM x 256 bf16 GEMM, 8 waves, 2-phase (24-MFMA clusters) ----------------
// v2 of round-6 kernel: all 20 fragment reads in ph1, 4 barriers/tile (was 8) — the
// transformation that won on gemm128. Hazards:
//  - ph1 reads of aC/bC drain (lgkm before MM) before ph1-end BAR => ph2's B(T+2)->bC
//    stage and next-tile's A-stage into aN are WAR-safe.
//  - per-thread vmcnt(4) at ph2 drains A(T+1)x3 and all older B => tile T+1 landed.
template<int BM>
__global__ __launch_bounds__(512, 2) void gemm_t(const u16* __restrict__ A, const u16* __restrict__ Bt,
    const float* __restrict__ bq, const float* __restrict__ bk, const float* __restrict__ bv,
    u16* __restrict__ Cb, float* __restrict__ Cf, int N, int K) {
  constexpr int CA = BM / 64;
  constexpr int MI = BM / 64;
  __shared__ alignas(16) u16 Asl[2][BM * 64];
  __shared__ alignas(16) u16 Bsl[2][256 * 64];
  int tid = threadIdx.x, wid = tid >> 6, lane = tid & 63;
  int lr = lane & 15, kg = lane >> 4;
  int gx = gridDim.x, nwg = gx * gridDim.y;
  int lid = blockIdx.y * gx + blockIdx.x;
  int q = nwg >> 3, r = nwg & 7;
  int xcd = lid & 7, idx = lid >> 3;
  int swz = (xcd < r ? xcd * (q + 1) : r * (q + 1) + (xcd - r) * q) + idx;
  int m0 = (swz / gx) * BM, n0 = (swz % gx) * 256;
  const u16* Ap = A + (size_t)m0 * K;
  const u16* Bp = Bt + (size_t)n0 * K;
  int wm = wid >> 2, wn = wid & 3;
  f32x4 acc[2][2][MI][2] = {};
  int NT = K >> 6;

  auto STAGEC = [&](const u16* gp, int tile, int chunk, u16* base) {
    int p = tid * 16;
    int row = (chunk << 6) + (p >> 7);
    int gcb = (p & 127) ^ ((row & 7) << 4);
    const char* src = (const char*)gp + ((size_t)row * K + (tile << 6)) * 2 + gcb;
    char* dst = (char*)base + (chunk << 13) + (wid << 10);
    GLOAD16(src, dst);
  };
  auto LDA = [&](short8 (&af)[MI][2], const u16* base, int qm) {
    #pragma unroll
    for (int mi = 0; mi < MI; mi++)
      #pragma unroll
      for (int ks = 0; ks < 2; ks++)
        af[mi][ks] = ldsfrag(base, wm * (BM / 2) + qm * (BM / 4) + mi * 16 + lr, ks, kg);
  };
  auto LDB = [&](short8 (&bf)[2][2], const u16* base, int qn) {
    #pragma unroll
    for (int ni = 0; ni < 2; ni++)
      #pragma unroll
      for (int ks = 0; ks < 2; ks++)
        bf[ni][ks] = ldsfrag(base, wn * 64 + qn * 32 + ni * 16 + lr, ks, kg);
  };
  auto MM = [&](f32x4 (&a)[MI][2], short8 (&af)[MI][2], short8 (&bf)[2][2]) {
    #pragma unroll
    for (int ks = 0; ks < 2; ks++)
      #pragma unroll
      for (int mi = 0; mi < MI; mi++)
        #pragma unroll
        for (int ni = 0; ni < 2; ni++)
          a[mi][ni] = __builtin_amdgcn_mfma_f32_16x16x32_bf16(af[mi][ks], bf[ni][ks], a[mi][ni], 0, 0, 0);
  };
  #define BAR() __builtin_amdgcn_s_barrier()
  #define SB()  __builtin_amdgcn_sched_barrier(0)
  #define VMCNT(n) asm volatile("s_waitcnt vmcnt(" #n ")" ::: "memory")

  #pragma unroll
  for (int c = 0; c < CA; c++) STAGEC(Ap, 0, c, &Asl[0][0]);
  #pragma unroll
  for (int c = 0; c < 4; c++) STAGEC(Bp, 0, c, &Bsl[0][0]);
  #pragma unroll
  for (int c = 0; c < 4; c++) STAGEC(Bp, 1, c, &Bsl[1][0]);
  VMCNT(4);
  BAR();

  short8 af0[MI][2], af1[MI][2], bfA[2][2], bfB[2][2];
  for (int T = 0; T < NT; T++) {
    int par = T & 1;
    u16* aC = &Asl[par][0];
    u16* bC = &Bsl[par][0];
    u16* aN = &Asl[par ^ 1][0];
    int tA = T + 1 < NT ? T + 1 : NT - 1;   // tail clamps: benign rewrites
    int tB = T + 2 < NT ? T + 2 : NT - 1;
    // ph1: ALL fragment reads + stage A(T+1); 24-MFMA cluster (qm=0)
    LDA(af0, aC, 0); LDA(af1, aC, 1); LDB(bfA, bC, 0); LDB(bfB, bC, 1);
    #pragma unroll
    for (int c = 0; c < CA; c++) STAGEC(Ap, tA, c, aN);
    SB(); BAR();
    __builtin_amdgcn_s_setprio(1);
    MM(acc[0][0], af0, bfA); MM(acc[0][1], af0, bfB);
    __builtin_amdgcn_s_setprio(0);
    BAR();
    // ph2: stage B(T+2); vmcnt(4) -> T+1 fully landed; 24-MFMA cluster (qm=1)
    STAGEC(Bp, tB, 0, bC); STAGEC(Bp, tB, 1, bC);
    STAGEC(Bp, tB, 2, bC); STAGEC(Bp, tB, 3, bC);
    VMCNT(4);
    SB(); BAR();
    __builtin_amdgcn_s_setprio(1);
    MM(acc[1][0], af1, bfA); MM(acc[1][1], af1, bfB);
    __builtin_amdgcn_s_setprio(0);
    BAR();
  }
  #undef BAR
  #undef SB
  #undef VMCNT

  #pragma unroll
  for (int qm = 0; qm < 2; qm++)
    #pragma unroll
    for (int qn = 0; qn < 2; qn++)
      #pragma unroll
      for (int mi = 0; mi < MI; mi++)
        #pragma unroll
        for (int ni = 0; ni < 2; ni++) {
          int col = n0 + wn * 64 + qn * 32 + ni * 16 + lr;
          int rbase = m0 + wm * (BM / 2) + qm * (BM / 4) + mi * 16 + kg * 4;
          #pragma unroll
          for (int rr = 0; rr < 4; rr++) {
            int row = rbase + rr;
            float v = acc[qm][qn][mi][ni][rr];
            if (bq) v += row < 4096 ? bq[row] : (row < 5120 ? bk[row - 4096] : bv[row - 5120]);
            if (Cf) Cf[(size_t)row * N + col] = v;
            else    Cb[(size_t)row * N + col] = f2bf(v);
          }
        }
}

// ---------------- 128x128 bf16 GEMM, 4 waves, 2 blocks/CU, 2-phase (16-MFMA clusters) ----------------
__global__ __launch_bounds__(256, 2) void gemm128(const u16* __restrict__ A, const u16* __restrict__ Bt,
                                                  float* __restrict__ Cf, int N, int K) {
  __shared__ alignas(16) u16 Asl[2][128 * 64];
  __shared__ alignas(16) u16 Bsl[2][128 * 64];
  int tid = threadIdx.x, wid = tid >> 6, lane = tid & 63;
  int lr = lane & 15, kg = lane >> 4;
  int gx = gridDim.x, nwg = gx * gridDim.y;
  int lid = blockIdx.y * gx + blockIdx.x;
  int q = nwg >> 3, r = nwg & 7;
  int xcd = lid & 7, idx = lid >> 3;
  int swz = (xcd < r ? xcd * (q + 1) : r * (q + 1) + (xcd - r) * q) + idx;
  int m0 = (swz / gx) * 128, n0 = (swz % gx) * 128;
  const u16* Ap = A + (size_t)m0 * K;
  const u16* Bp = Bt + (size_t)n0 * K;
  int wr = wid >> 1, wc = wid & 1;
  f32x4 acc[2][2][2][2] = {};
  int NT = K >> 6;

  auto STAGEC = [&](const u16* gp, int tile, int chunk, u16* base) {
    int p = (chunk << 12) + tid * 16;
    int row = p >> 7;
    int gcb = (p & 127) ^ ((row & 7) << 4);
    const char* src = (const char*)gp + ((size_t)row * K + (tile << 6)) * 2 + gcb;
    char* dst = (char*)base + (chunk << 12) + (wid << 10);
    GLOAD16(src, dst);
  };
  auto LDA = [&](short8 (&af)[2][2], const u16* base, int qm) {
    #pragma unroll
    for (int mi = 0; mi < 2; mi++)
      #pragma unroll
      for (int ks = 0; ks < 2; ks++)
        af[mi][ks] = ldsfrag(base, wr * 64 + qm * 32 + mi * 16 + lr, ks, kg);
  };
  auto LDB = [&](short8 (&bf)[2][2], const u16* base, int qn) {
    #pragma unroll
    for (int ni = 0; ni < 2; ni++)
      #pragma unroll
      for (int ks = 0; ks < 2; ks++)
        bf[ni][ks] = ldsfrag(base, wc * 64 + qn * 32 + ni * 16 + lr, ks, kg);
  };
  auto MM = [&](f32x4 (&a)[2][2], short8 (&af)[2][2], short8 (&bf)[2][2]) {
    #pragma unroll
    for (int ks = 0; ks < 2; ks++)
      #pragma unroll
      for (int mi = 0; mi < 2; mi++)
        #pragma unroll
        for (int ni = 0; ni < 2; ni++)
          a[mi][ni] = __builtin_amdgcn_mfma_f32_16x16x32_bf16(af[mi][ks], bf[ni][ks], a[mi][ni], 0, 0, 0);
  };
  #define BAR() __builtin_amdgcn_s_barrier()
  #define SB()  __builtin_amdgcn_sched_barrier(0)
  #define VMCNT(n) asm volatile("s_waitcnt vmcnt(" #n ")" ::: "memory")

  #pragma unroll
  for (int c = 0; c < 4; c++) STAGEC(Ap, 0, c, &Asl[0][0]);
  #pragma unroll
  for (int c = 0; c < 4; c++) STAGEC(Bp, 0, c, &Bsl[0][0]);
  #pragma unroll
  for (int c = 0; c < 4; c++) STAGEC(Bp, 1, c, &Bsl[1][0]);
  VMCNT(4);
  BAR();

  short8 af0[2][2], af1[2][2], bfA[2][2], bfB[2][2];
  for (int T = 0; T < NT; T++) {
    int par = T & 1;
    u16* aC = &Asl[par][0];
    u16* bC = &Bsl[par][0];
    u16* aN = &Asl[par ^ 1][0];
    int tA = T + 1 < NT ? T + 1 : NT - 1;
    int tB = T + 2 < NT ? T + 2 : NT - 1;
    // ph1
    LDA(af0, aC, 0); LDA(af1, aC, 1); LDB(bfA, bC, 0); LDB(bfB, bC, 1);
    STAGEC(Ap, tA, 0, aN); STAGEC(Ap, tA, 1, aN);
    STAGEC(Ap, tA, 2, aN); STAGEC(Ap, tA, 3, aN);
    SB(); BAR();
    __builtin_amdgcn_s_setprio(1);
    MM(acc[0][0], af0, bfA); MM(acc[0][1], af0, bfB);
    __builtin_amdgcn_s_setprio(0);
    BAR();
    // ph2
    STAGEC(Bp, tB, 0, bC); STAGEC(Bp, tB, 1, bC);
    STAGEC(Bp, tB, 2, bC); STAGEC(Bp, tB, 3, bC);
    VMCNT(4);
    SB(); BAR();
    __builtin_amdgcn_s_setprio(1);
    MM(acc[1][0], af1, bfA); MM(acc[1][1], af1, bfB);
    __builtin_amdgcn_s_setprio(0);
    BAR();
  }
  #undef BAR
  #undef SB
  #undef VMCNT

  #pragma unroll
  for (int qm = 0; qm < 2; qm++)
    #pragma unroll
    for (int qn = 0; qn < 2; qn++)
      #pragma unroll
      for (int mi = 0; mi < 2; mi++)
        #pragma unroll
        for (int ni = 0; ni < 2; ni++) {
          int col = n0 + wc * 64 + qn * 32 + ni * 16 + lr;
          int rbase = m0 + wr * 64 + qm * 32 + mi * 16 + kg * 4;
          #pragma unroll
          for (int rr = 0; rr < 4; rr++)
            Cf[(size_t)(rbase + rr) * N + col] = acc[qm][qn][mi][ni][rr];
        }
}

// ---------------- RoPE + transpose (Q and K heads in one launch) ----------------
__global__ __launch_bounds__(256) void rope2_kernel(const u16* __restrict__ qin,
                                                    const u16* __restrict__ kin,
                                                    u16* __restrict__ qout,
                                                    u16* __restrict__ kout,
                                                    const float* __restrict__ cp,
                                                    const float* __restrict__ sp) {
  __shared__ u16 t[128][33];
  int hh = blockIdx.x;
  bool isQ = hh < H_;
  int h = isQ ? hh : hh - H_;
  const u16* in = (isQ ? qin : kin) + (size_t)h * 128 * S_;
  u16* out = (isQ ? qout : kout) + (size_t)h * S_ * D_;
  float oscale = isQ ? 0.1275176329533421f : 1.0f;   // log2(e)/sqrt(128) folded into Q
  int s0 = blockIdx.y * 32;
  int tid = threadIdx.x;
  #pragma unroll
  for (int i = 0; i < 16; i++) {
    int idx = tid + i * 256;
    int row = idx >> 5, sc = idx & 31;
    t[row][sc] = in[(size_t)row * S_ + s0 + sc];
  }
  __syncthreads();
  int d = tid & 127, sh = tid >> 7;
  int dl = d & 63;
  bool hi = d >= 64;
  #pragma unroll
  for (int j = 0; j < 16; j++) {
    int sl = sh * 16 + j;
    int s = s0 + sl;
    float x = bf2f(t[d][sl]);
    float p = bf2f(t[d ^ 64][sl]);
    float c  = cp[(size_t)s * D_ + dl];
    float sn = sp[(size_t)s * D_ + dl];
    float o = hi ? fmaf(p, sn, x * c) : fmaf(-p, sn, x * c);
    out[(size_t)s * D_ + d] = f2bf(o * oscale);
  }
}

// ---------------- flash attention v2 (causal GQA, swapped-QK, staged KV) ----------------
__global__ __launch_bounds__(256) void attn_v2(const u16* __restrict__ Q, const u16* __restrict__ K,
                                               const u16* __restrict__ V, u16* __restrict__ Ot) {
  __shared__ alignas(16) u16 Ks[2][64 * 128];
  __shared__ alignas(16) u16 Vs[2][128 * 64];
  __shared__ alignas(16) u16 Pl[4][2][16 * 64];
  int h = blockIdx.x;
  int qtile = (int)(gridDim.y - 1) - (int)blockIdx.y;   // heavy first
  int kv = h >> 2;
  int tid = threadIdx.x, wid = tid >> 6, lane = tid & 63;
  int lr = lane & 15, kg = lane >> 4;
  int q0w = qtile * 128 + wid * 32;
  const u16* Qb = Q + ((size_t)h * S_ + q0w) * D_;
  const u16* Kb = K + (size_t)kv * S_ * D_;
  const u16* Vb = V + (size_t)kv * D_ * S_;
  int sw = (lr & 7) << 3;

  short8 qf[2][4];
  #pragma unroll
  for (int m = 0; m < 2; m++)
    #pragma unroll
    for (int kk = 0; kk < 4; kk++)
      qf[m][kk] = *(const short8a*)(Qb + (size_t)(m * 16 + lr) * D_ + kk * 32 + kg * 8);

  f32x4 acc[2][8] = {};
  float mreg[2] = {-1e30f, -1e30f};
  float lsum[2] = {0.f, 0.f};

  int krow[4], kcb[4], vrow[4], vcb[4];
  #pragma unroll
  for (int j = 0; j < 4; j++) {
    int c = wid * 4 + j;
    int o = c * 1024 + lane * 16;
    krow[j] = o >> 8;
    kcb[j] = (o & 255) ^ ((krow[j] & 7) << 4);
    vrow[j] = o >> 7;
    vcb[j] = (o & 127) ^ ((vrow[j] & 7) << 4);
  }

  int nlt = 2 * qtile + 2;
  #pragma unroll
  for (int j = 0; j < 4; j++) {
    int c = wid * 4 + j;
    GLOAD16((const char*)Kb + ((size_t)krow[j] * D_) * 2 + kcb[j], (char*)Ks[0] + c * 1024);
    GLOAD16((const char*)Vb + ((size_t)vrow[j] * S_) * 2 + vcb[j], (char*)Vs[0] + c * 1024);
  }
  int cur = 0;
  for (int t = 0; t < nlt; t++) {
    __syncthreads();
    if (t + 1 < nlt) {
      int l1 = (t + 1) * 64;
      #pragma unroll
      for (int j = 0; j < 4; j++) {
        int c = wid * 4 + j;
        GLOAD16((const char*)Kb + ((size_t)(l1 + krow[j]) * D_) * 2 + kcb[j],
                (char*)Ks[cur ^ 1] + c * 1024);
        GLOAD16((const char*)Vb + ((size_t)vrow[j] * S_ + l1) * 2 + vcb[j],
                (char*)Vs[cur ^ 1] + c * 1024);
      }
    }
    int l0 = t * 64;
    bool act0 = l0 <= q0w + 15;
    bool act1 = l0 <= q0w + 31;
    if (act1) {
      const u16* Kc = Ks[cur];
      const u16* Vc = Vs[cur];
      f32x4 st[2][4] = {};
      #pragma unroll
      for (int ls = 0; ls < 4; ls++) {
        short8 kf[4];
        #pragma unroll
        for (int kk = 0; kk < 4; kk++)
          kf[kk] = *(const short8a*)&Kc[(ls * 16 + lr) * 128 + ((kk * 32 + kg * 8) ^ sw)];
        #pragma unroll
        for (int kk = 0; kk < 4; kk++) {
          st[0][ls] = __builtin_amdgcn_mfma_f32_16x16x32_bf16(kf[kk], qf[0][kk], st[0][ls], 0, 0, 0);
          st[1][ls] = __builtin_amdgcn_mfma_f32_16x16x32_bf16(kf[kk], qf[1][kk], st[1][ls], 0, 0, 0);
        }
      }
      #pragma unroll
      for (int m = 0; m < 2; m++) {
        bool act = m ? act1 : act0;
        if (!act) continue;
        int qrow = q0w + m * 16 + lr;
        if (l0 + 63 > q0w + m * 16) {
          #pragma unroll
          for (int ls = 0; ls < 4; ls++)
            #pragma unroll
            for (int rr = 0; rr < 4; rr++) {
              int l = l0 + ls * 16 + kg * 4 + rr;
              st[m][ls][rr] = (l <= qrow) ? st[m][ls][rr] : -1e30f;
            }
        }
        float rmax;
        {
          float a0 = fmaxf(fmaxf(st[m][0][0], st[m][0][1]), fmaxf(st[m][0][2], st[m][0][3]));
          float a1 = fmaxf(fmaxf(st[m][1][0], st[m][1][1]), fmaxf(st[m][1][2], st[m][1][3]));
          float a2 = fmaxf(fmaxf(st[m][2][0], st[m][2][1]), fmaxf(st[m][2][2], st[m][2][3]));
          float a3 = fmaxf(fmaxf(st[m][3][0], st[m][3][1]), fmaxf(st[m][3][2], st[m][3][3]));
          rmax = fmaxf(fmaxf(a0, a1), fmaxf(a2, a3));
        }
        rmax = fmaxf(rmax, __shfl_xor(rmax, 16, 64));
        rmax = fmaxf(rmax, __shfl_xor(rmax, 32, 64));
        if (__any(rmax > mreg[m] + 8.0f)) {
          float nm = fmaxf(mreg[m], rmax);
          float f = __builtin_amdgcn_exp2f(mreg[m] - nm);
          mreg[m] = nm;
          lsum[m] *= f;
          float fr0 = __shfl(f, kg * 4 + 0, 64);
          float fr1 = __shfl(f, kg * 4 + 1, 64);
          float fr2 = __shfl(f, kg * 4 + 2, 64);
          float fr3 = __shfl(f, kg * 4 + 3, 64);
          #pragma unroll
          for (int dc = 0; dc < 8; dc++) {
            acc[m][dc][0] *= fr0; acc[m][dc][1] *= fr1;
            acc[m][dc][2] *= fr2; acc[m][dc][3] *= fr3;
          }
        }
        float e[4][4];
        #pragma unroll
        for (int ls = 0; ls < 4; ls++)
          #pragma unroll
          for (int rr = 0; rr < 4; rr++)
            e[ls][rr] = __builtin_amdgcn_exp2f(st[m][ls][rr] - mreg[m]);
        float rs = 0.f;
        #pragma unroll
        for (int ls = 0; ls < 4; ls++)
          rs += (e[ls][0] + e[ls][1]) + (e[ls][2] + e[ls][3]);
        rs += __shfl_xor(rs, 16, 64);
        rs += __shfl_xor(rs, 32, 64);
        lsum[m] += rs;
        u16* Pw = &Pl[wid][m][0];
        #pragma unroll
        for (int ls = 0; ls < 4; ls++) {
          __hip_bfloat162 p01 = __float22bfloat162_rn(float2{e[ls][0], e[ls][1]});
          __hip_bfloat162 p23 = __float22bfloat162_rn(float2{e[ls][2], e[ls][3]});
          uint2 pk;
          pk.x = *(u32*)&p01;
          pk.y = *(u32*)&p23;
          *(uint2*)&Pw[lr * 64 + ((ls * 16 + kg * 4) ^ sw)] = pk;
        }
      }
      #pragma unroll
      for (int kk = 0; kk < 2; kk++) {
        short8 pf0 = {}, pf1;
        if (act0) pf0 = *(const short8a*)&Pl[wid][0][lr * 64 + ((kk * 32 + kg * 8) ^ sw)];
        pf1 = *(const short8a*)&Pl[wid][1][lr * 64 + ((kk * 32 + kg * 8) ^ sw)];
        #pragma unroll
        for (int dc = 0; dc < 8; dc++) {
          short8 vf = *(const short8a*)&Vc[(dc * 16 + lr) * 64 + ((kk * 32 + kg * 8) ^ sw)];
          if (act0) acc[0][dc] = __builtin_amdgcn_mfma_f32_16x16x32_bf16(pf0, vf, acc[0][dc], 0, 0, 0);
          acc[1][dc] = __builtin_amdgcn_mfma_f32_16x16x32_bf16(pf1, vf, acc[1][dc], 0, 0, 0);
        }
      }
    }
    cur ^= 1;
  }
  #pragma unroll
  for (int m = 0; m < 2; m++) {
    float inv0 = 1.0f / __shfl(lsum[m], kg * 4 + 0, 64);
    float inv1 = 1.0f / __shfl(lsum[m], kg * 4 + 1, 64);
    float inv2 = 1.0f / __shfl(lsum[m], kg * 4 + 2, 64);
    float inv3 = 1.0f / __shfl(lsum[m], kg * 4 + 3, 64);
    #pragma unroll
    for (int dc = 0; dc < 8; dc++) {
      int col = h * D_ + dc * 16 + lr;
      int qg = q0w + m * 16 + kg * 4;
      Ot[(size_t)(qg + 0) * HID_ + col] = f2bf(acc[m][dc][0] * inv0);
      Ot[(size_t)(qg + 1) * HID_ + col] = f2bf(acc[m][dc][1] * inv1);
      Ot[(size_t)(qg + 2) * HID_ + col] = f2bf(acc[m][dc][2] * inv2);
      Ot[(size_t)(qg + 3) * HID_ + col] = f2bf(acc[m][dc][3] * inv3);
    }
  }
}

// ---------------- workspace layout (bytes) ----------------
static constexpr size_t OFF_WQKV = 0;           // 50331648 (6144x4096 bf16); reused post-QKV-gemm
static constexpr size_t OFF_WO   = 50331648;    // 33554432 (4096x4096 bf16)
static constexpr size_t OFF_XT   = 83886080;    // 16777216 (2048x4096 bf16)
static constexpr size_t OFF_QKVC = 100663296;   // 25165824 -> total 125829120

extern "C" void kernel_launch(void* const* d_in, const int* in_sizes, int n_in,
                              void* d_out, int out_size, void* d_ws, size_t ws_size,
                              hipStream_t stream) {
  const float* x    = (const float*)d_in[0];
  const float* wq   = (const float*)d_in[1];
  const float* bq   = (const float*)d_in[2];
  const float* wk   = (const float*)d_in[3];
  const float* bk   = (const float*)d_in[4];
  const float* wv   = (const float*)d_in[5];
  const float* bv   = (const float*)d_in[6];
  const float* wo   = (const float*)d_in[7];
  const float* cosP = (const float*)d_in[8];
  const float* sinP = (const float*)d_in[9];
  char* ws = (char*)d_ws;
  u16* WQKV = (u16*)(ws + OFF_WQKV);
  u16* WO   = (u16*)(ws + OFF_WO);
  u16* XT   = (u16*)(ws + OFF_XT);
  u16* QKVC = (u16*)(ws + OFF_QKVC);
  u16* QT   = QKVC;
  u16* KT   = QKVC + (size_t)4096 * S_;
  u16* VB   = QKVC + (size_t)5120 * S_;
  u16* QATT = (u16*)(ws + 0);
  u16* KATT = (u16*)(ws + 16777216);
  u16* OT   = (u16*)(ws + 20971520);
  float* y = (float*)d_out;

  // 1) fused weight casts
  cast4_kernel<<<2048, 256, 0, stream>>>(
      wq, wk, wv, wo,
      WQKV, WQKV + (size_t)4096 * HID_, WQKV + (size_t)5120 * HID_, WO,
      (HID_ * HID_) / 4, (KV_ * D_ * HID_) / 4, (KV_ * D_ * HID_) / 4, (HID_ * HID_) / 4);
  // 2) X^T
  transpose_cast_kernel<<<dim3(S_ / 32, HID_ / 32), 256, 0, stream>>>(x, XT);
  // 3) fused QKV projection (M=6144), BM=192 2-phase schedule, 256 blocks
  gemm_t<192><<<dim3(S_ / 256, 6144 / 192), 512, 0, stream>>>(WQKV, XT, bq, bk, bv,
                                                              QKVC, nullptr, S_, HID_);
  // 4) RoPE + transpose (Q scaled by log2e/sqrt(D)), one launch for Q+K heads
  rope2_kernel<<<dim3(H_ + KV_, S_ / 32), 256, 0, stream>>>(QT, KT, QATT, KATT, cosP, sinP);
  // 5) causal GQA flash attention -> O^T (S, H*D)
  attn_v2<<<dim3(H_, S_ / 128), 256, 0, stream>>>(QATT, KATT, VB, OT);
  // 6) output projection: 128x128, 4-wave, 2 blocks/CU, 2-phase schedule -> fp32 d_out
  gemm128<<<dim3(S_ / 128, HID_ / 128), 256, 0, stream>>>(WO, OT, y, S_, HID_);
}